// Round 8
// baseline (1317.232 us; speedup 1.0000x reference)
//
#include <hip/hip_runtime.h>
#include <hip/hip_bf16.h>
#include <math.h>

#define T_STEPS 12
#define NNODES  20000
#define NEDGES  320000
#define MPAD    20032
#define FIN     128
#define HG      256
#define RS_STRIDE 20032

typedef unsigned short u16;
typedef unsigned int   u32;
using bf16x8 = __attribute__((ext_vector_type(8))) short;
using f32x4  = __attribute__((ext_vector_type(4))) float;

__device__ __forceinline__ float bf2f(u16 u) {
    union { u32 i; float f; } v; v.i = ((u32)u) << 16; return v.f;
}
__device__ __forceinline__ u16 f2bf(float f) {
    union { float f; u32 i; } v; v.f = f;
    u32 r = v.i + 0x7fffu + ((v.i >> 16) & 1u);
    return (u16)(r >> 16);
}
__device__ __forceinline__ u16 f2h(float f) {
    _Float16 h = (_Float16)f; u16 u; __builtin_memcpy(&u, &h, 2); return u;
}
__device__ __forceinline__ float h2f(u16 u) {
    _Float16 h; __builtin_memcpy(&h, &u, 2); return (float)h;
}
__device__ __forceinline__ void gload16(const void* g, void* l) {
    __builtin_amdgcn_global_load_lds(
        (const __attribute__((address_space(1))) u32*)g,
        (__attribute__((address_space(3))) u32*)l, 16, 0, 0);
}
__device__ __forceinline__ float sigm(float x) { return 1.f / (1.f + expf(-x)); }
__device__ __forceinline__ void astore(float* p, float v) {
    __hip_atomic_store(p, v, __ATOMIC_RELAXED, __HIP_MEMORY_SCOPE_AGENT);
}
__device__ __forceinline__ float aload(const float* p) {
    return __hip_atomic_load(p, __ATOMIC_RELAXED, __HIP_MEMORY_SCOPE_AGENT);
}

// ---------------- CSR build ----------------

__global__ void hist_kernel(const int* __restrict__ edges, int* __restrict__ hist) {
    int idx = blockIdx.x * blockDim.x + threadIdx.x;
    if (idx >= T_STEPS * NEDGES) return;
    int t = idx / NEDGES, e = idx - t * NEDGES;
    int d = edges[t * 2 * NEDGES + NEDGES + e];
    atomicAdd(&hist[t * NNODES + d], 1);
}

__global__ void __launch_bounds__(1024) scan_kernel(int* __restrict__ hist,
        int* __restrict__ rowstart, float* __restrict__ dinv) {
    int t = blockIdx.x;
    int tid = threadIdx.x;
    int wid = tid >> 6, lane = tid & 63;
    __shared__ int wsum[16];
    __shared__ int carry_s;
    if (tid == 0) carry_s = 0;
    __syncthreads();
    for (int base = 0; base < NNODES; base += 1024) {
        int i = base + tid;
        int orig = (i < NNODES) ? hist[t * NNODES + i] : 0;
        int v = orig;
#pragma unroll
        for (int off = 1; off < 64; off <<= 1) {
            int n = __shfl_up(v, off);
            if (lane >= off) v += n;
        }
        if (lane == 63) wsum[wid] = v;
        __syncthreads();
        if (wid == 0 && lane < 16) {
            int s = wsum[lane];
#pragma unroll
            for (int off = 1; off < 16; off <<= 1) {
                int n = __shfl_up(s, off);
                if (lane >= off) s += n;
            }
            wsum[lane] = s;
        }
        __syncthreads();
        int incl = v + (wid > 0 ? wsum[wid - 1] : 0) + carry_s;
        int excl = incl - orig;
        if (i < NNODES) {
            rowstart[t * RS_STRIDE + i] = excl;
            dinv[t * NNODES + i] = rsqrtf((float)(orig + 1));
            hist[t * NNODES + i] = 0;
        }
        __syncthreads();
        if (tid == 0) carry_s += wsum[15];
        __syncthreads();
    }
    if (tid == 0) rowstart[t * RS_STRIDE + NNODES] = carry_s;
}

__global__ void fill_kernel(const int* __restrict__ edges, const int* __restrict__ rowstart,
        int* __restrict__ cursor, int* __restrict__ col) {
    int idx = blockIdx.x * blockDim.x + threadIdx.x;
    if (idx >= T_STEPS * NEDGES) return;
    int t = idx / NEDGES, e = idx - t * NEDGES;
    int s = edges[t * 2 * NEDGES + e];
    int d = edges[t * 2 * NEDGES + NEDGES + e];
    int pos = rowstart[t * RS_STRIDE + d] + atomicAdd(&cursor[t * NNODES + d], 1);
    col[t * NEDGES + pos] = s;
}

// ---------------- conversions ----------------

__global__ void convw_kernel(const float* __restrict__ W, u16* __restrict__ Wt, int K) {
    int idx = blockIdx.x * blockDim.x + threadIdx.x;
    int n = idx / K, k = idx - n * K;
    Wt[idx] = f2bf(W[k * HG + n]);
}

__global__ void x2bf_kernel(const float* __restrict__ x, const float* __restrict__ dinv,
        u16* __restrict__ xb) {
    int idx = blockIdx.x * blockDim.x + threadIdx.x;
    int row = idx >> 5, q = (idx & 31) << 2;
    float dn = dinv[row];
    float4 v = *(const float4*)&x[(size_t)row * FIN + q];
    ushort4 o;
    o.x = f2bf(dn * v.x); o.y = f2bf(dn * v.y);
    o.z = f2bf(dn * v.z); o.w = f2bf(dn * v.w);
    *(ushort4*)&xb[(size_t)row * FIN + q] = o;
}

// ---------------- scalar-index XCD-sliced aggregation ----------------
// One NODE per WAVE: edge stream is wave-uniform. 64 indices fetched with one
// vector load; each edge's index extracted via readlane -> SGPR -> scalar row
// base, row load is saddr + 2B*lane (64-dim slice, one dim per lane).
// Per-edge per-lane cost: 1 load + 1 cvt + 1 add; SALU does index/addr work.
// slice = bid % NSLICE keeps each XCD's L2 on one 64-dim slice (2.56 MB).
// rows PRE-SCALED by dinv: out[d] = dinv[d]*(row[d] + sum_{s->d} row[s]).

template <int DIMS, int NSLICE, bool SRC_MPAD>
__global__ void __launch_bounds__(256) agg_scalar(const u16* __restrict__ src,
        const int* __restrict__ rowstart, const int* __restrict__ col,
        const float* __restrict__ dinv, u16* __restrict__ out) {
    constexpr int NPB = MPAD / 4;
    int bid = blockIdx.x;
    int slice = bid % NSLICE;
    int rest = bid / NSLICE;
    int nq = rest % NPB;
    int t = rest / NPB;
    int wid = threadIdx.x >> 6, lane = threadIdx.x & 63;
    int node = nq * 4 + wid;
    int dbase = slice * 64 + lane;
    u16* op = out + ((size_t)t * MPAD + node) * DIMS + dbase;
    if (node >= NNODES) { *op = 0; return; }
    const u16* xt = src + (size_t)t * (SRC_MPAD ? MPAD : NNODES) * DIMS + dbase;
    const int* cb = col + (size_t)t * NEDGES;
    float acc = bf2f(xt[(size_t)node * DIMS]);
    int s0 = rowstart[t * RS_STRIDE + node], s1 = rowstart[t * RS_STRIDE + node + 1];
    for (int e0 = s0; e0 < s1; e0 += 64) {
        int cnt = s1 - e0; if (cnt > 64) cnt = 64;
        int idxv = cb[e0 + (lane < cnt ? lane : 0)];
        int j = 0;
        for (; j + 8 <= cnt; j += 8) {
            float v[8];
#pragma unroll
            for (int q = 0; q < 8; ++q) {
                int sj = __builtin_amdgcn_readlane(idxv, j + q);
                v[q] = bf2f(xt[(size_t)sj * DIMS]);
            }
#pragma unroll
            for (int q = 0; q < 8; ++q) acc += v[q];
        }
        for (; j < cnt; ++j) {
            int sj = __builtin_amdgcn_readlane(idxv, j);
            acc += bf2f(xt[(size_t)sj * DIMS]);
        }
    }
    *op = f2bf(dinv[t * NNODES + node] * acc);
}

// ---------------- bf16 MFMA GEMM, 64M x 256N tile (verified R7) ----------------

template <int K, bool POOL>
__global__ __launch_bounds__(256) void gemm_bf16(
        const u16* __restrict__ A, const u16* __restrict__ Bt,
        const float* __restrict__ bias, const float* __restrict__ dscale,
        u16* __restrict__ C, float* __restrict__ pool) {
    __shared__ u16 As[64 * 64];      // 8 KB
    __shared__ u16 Bs[256 * 64];     // 32 KB
    __shared__ float csum[HG];
    int tid = threadIdx.x;
    int bm = blockIdx.x * 64;
    int t8 = tid >> 3, sl = tid & 7;
    int lane = tid & 63, w = tid >> 6;
    int r0 = lane & 15, gq = lane >> 4;
    int tblk = blockIdx.x / 313;

    f32x4 acc[4][4] = {};

    for (int k0 = 0; k0 < K; k0 += 64) {
#pragma unroll
        for (int i = 0; i < 2; ++i) {
            int r = i * 32 + t8;
            int ch = sl ^ (r & 7);
            gload16(A + (size_t)(bm + r) * K + k0 + ch * 8, &As[i * 2048 + tid * 8]);
        }
#pragma unroll
        for (int i = 0; i < 8; ++i) {
            int r = i * 32 + t8;
            int ch = sl ^ (r & 7);
            gload16(Bt + (size_t)r * K + k0 + ch * 8, &Bs[i * 2048 + tid * 8]);
        }
        __syncthreads();
#pragma unroll
        for (int kk = 0; kk < 2; ++kk) {
            bf16x8 a[4], b[4];
#pragma unroll
            for (int mi = 0; mi < 4; ++mi) {
                int R = mi * 16 + r0;
                int s = (kk * 4 + gq) ^ (R & 7);
                a[mi] = *(const bf16x8*)&As[R * 64 + s * 8];
            }
#pragma unroll
            for (int ni = 0; ni < 4; ++ni) {
                int R = w * 64 + ni * 16 + r0;
                int s = (kk * 4 + gq) ^ (R & 7);
                b[ni] = *(const bf16x8*)&Bs[R * 64 + s * 8];
            }
#pragma unroll
            for (int mi = 0; mi < 4; ++mi)
#pragma unroll
                for (int ni = 0; ni < 4; ++ni)
                    acc[mi][ni] = __builtin_amdgcn_mfma_f32_16x16x32_bf16(
                        a[mi], b[ni], acc[mi][ni], 0, 0, 0);
        }
        __syncthreads();
    }

    if (!POOL) {
#pragma unroll
        for (int ni = 0; ni < 4; ++ni) {
            int colg = w * 64 + ni * 16 + r0;
            float b = bias[colg];
#pragma unroll
            for (int mi = 0; mi < 4; ++mi) {
                int rbase = bm + mi * 16 + gq * 4;
#pragma unroll
                for (int q = 0; q < 4; ++q) {
                    int row = rbase + q;
                    int rloc = row - tblk * MPAD;
                    float sc = (rloc < NNODES) ? dscale[tblk * NNODES + rloc] : 0.f;
                    C[(size_t)row * HG + colg] = f2bf(sc * fmaxf(acc[mi][ni][q] + b, 0.f));
                }
            }
        }
    } else {
        csum[tid] = 0.f;
        __syncthreads();
#pragma unroll
        for (int ni = 0; ni < 4; ++ni) {
            int colg = w * 64 + ni * 16 + r0;
            float b = bias[colg];
            float s = 0.f;
#pragma unroll
            for (int mi = 0; mi < 4; ++mi) {
                int rbase = bm + mi * 16 + gq * 4;
#pragma unroll
                for (int q = 0; q < 4; ++q) {
                    int row = rbase + q;
                    int rloc = row - tblk * MPAD;
                    if (rloc < NNODES) s += fmaxf(acc[mi][ni][q] + b, 0.f);
                }
            }
            atomicAdd(&csum[colg], s);
        }
        __syncthreads();
        atomicAdd(&pool[tblk * HG + tid], csum[tid]);
    }
}

// ---------------- layer-0 input projection ----------------

__global__ void __launch_bounds__(128) pre0_kernel(const float* __restrict__ pooled,
        const float* __restrict__ Wih0, const float* __restrict__ bih0,
        const float* __restrict__ bhh0, float* __restrict__ pre0) {
    int j = blockIdx.x * 128 + threadIdx.x;
    const float4* w = (const float4*)(Wih0 + (size_t)j * HG);
    float acc[T_STEPS];
#pragma unroll
    for (int t = 0; t < T_STEPS; ++t) acc[t] = 0.f;
    for (int i = 0; i < 64; ++i) {
        float4 wv = w[i];
#pragma unroll
        for (int t = 0; t < T_STEPS; ++t) {
            float4 pv = *(const float4*)&pooled[t * HG + i * 4];
            acc[t] += pv.x * wv.x + pv.y * wv.y + pv.z * wv.z + pv.w * wv.w;
        }
    }
    float b = bih0[j] + bhh0[j];
#pragma unroll
    for (int t = 0; t < T_STEPS; ++t)
        pre0[t * 1024 + j] = acc[t] * (1.f / (float)NNODES) + b;
}

// ---------------- 4-block cooperative LSTM (verified R5-R7) ----------------

__device__ __forceinline__ void run_layer(const float* __restrict__ W,
        const float* preSrc, int preStride,
        int r, int tid, int b, int sbase, bool save_hseq,
        float* hl, float* garr,
        float* hbuf, float* hseq_glob, int* flags) {
    int u = tid & 63;
    u32 wreg[128];
    {
        const float4* src = (const float4*)(W + (size_t)r * HG);
#pragma unroll
        for (int i = 0; i < 64; ++i) {
            float4 v = src[i];
            wreg[2 * i]     = (u32)f2h(v.x) | ((u32)f2h(v.y) << 16);
            wreg[2 * i + 1] = (u32)f2h(v.z) | ((u32)f2h(v.w) << 16);
        }
    }
    float c = 0.f;
    hl[tid] = 0.f;
    __syncthreads();
    for (int t = 0; t < T_STEPS; ++t) {
        int s = sbase + t + 1;
        float pv = preSrc[t * preStride];
        float acc = 0.f;
#pragma unroll
        for (int k2 = 0; k2 < 128; ++k2) {
            u32 w = wreg[k2];
            float2 hv = *(const float2*)&hl[k2 * 2];
            acc += h2f((u16)w) * hv.x + h2f((u16)(w >> 16)) * hv.y;
        }
        garr[tid] = acc + pv;
        __syncthreads();
        if (tid < 64) {
            float ig = sigm(garr[u]);
            float fg = sigm(garr[64 + u]);
            float gg = tanhf(garr[128 + u]);
            float og = sigm(garr[192 + u]);
            c = fg * c + ig * gg;
            float hn = og * tanhf(c);
            astore(&hbuf[(s & 1) * 256 + b * 64 + u], hn);
            if (save_hseq) astore(&hseq_glob[t * 256 + b * 64 + u], hn);
        }
        if (tid == 0)
            __hip_atomic_store(&flags[b], s, __ATOMIC_RELEASE, __HIP_MEMORY_SCOPE_AGENT);
        if (tid < 4) {
            while (__hip_atomic_load(&flags[tid], __ATOMIC_ACQUIRE,
                                     __HIP_MEMORY_SCOPE_AGENT) < s)
                __builtin_amdgcn_s_sleep(1);
        }
        __syncthreads();
        hl[tid] = aload(&hbuf[(s & 1) * 256 + tid]);
        __syncthreads();
    }
}

__global__ void __launch_bounds__(256, 1) lstm4(
        const float* __restrict__ pre0,
        const float* __restrict__ Whh0, const float* __restrict__ Wih1,
        const float* __restrict__ Whh1,
        const float* __restrict__ bih1, const float* __restrict__ bhh1,
        const float* __restrict__ Wlin, const float* __restrict__ blin,
        float* hbuf, float* hseq_glob, int* flags,
        float* __restrict__ out) {
    __shared__ float hseqL[T_STEPS * 256];
    __shared__ float pre1L[T_STEPS * 256];
    __shared__ float hl[256];
    __shared__ float garr[256];
    int tid = threadIdx.x;
    int b = blockIdx.x;
    int g = tid >> 6, u = tid & 63;
    int r = g * 256 + b * 64 + u;

    run_layer(Whh0, pre0 + r, 1024, r, tid, b, 0, true,
              hl, garr, hbuf, hseq_glob, flags);

    for (int i = tid; i < T_STEPS * 256; i += 256)
        hseqL[i] = aload(&hseq_glob[i]);
    __syncthreads();

    {
        float pre1[T_STEPS];
#pragma unroll
        for (int t = 0; t < T_STEPS; ++t) pre1[t] = 0.f;
        const float4* src = (const float4*)(Wih1 + (size_t)r * HG);
        for (int i = 0; i < 64; ++i) {
            float4 wv = src[i];
#pragma unroll
            for (int t = 0; t < T_STEPS; ++t) {
                float4 hv = *(const float4*)&hseqL[t * 256 + i * 4];
                pre1[t] += wv.x * hv.x + wv.y * hv.y + wv.z * hv.z + wv.w * hv.w;
            }
        }
        float bias1 = bih1[r] + bhh1[r];
        __syncthreads();
#pragma unroll
        for (int t = 0; t < T_STEPS; ++t) pre1L[t * 256 + tid] = pre1[t] + bias1;
        __syncthreads();
    }

    run_layer(Whh1, pre1L + tid, 256, r, tid, b, T_STEPS, false,
              hl, garr, hbuf, hseq_glob, flags);

    if (b == 0) {
        float hv = hl[tid];
        for (int j = 0; j < 8; ++j) {
            garr[tid] = hv * Wlin[j * 256 + tid];
            __syncthreads();
            if (tid < 128) garr[tid] += garr[tid + 128];
            __syncthreads();
            if (tid < 64) {
                float v = garr[tid] + garr[tid + 64];
                for (int off = 32; off; off >>= 1) v += __shfl_down(v, off);
                if (tid == 0) out[j] = v + blin[j];
            }
            __syncthreads();
        }
    }
}

// ---------------- orchestration ----------------

extern "C" void kernel_launch(void* const* d_in, const int* in_sizes, int n_in,
                              void* d_out, int out_size, void* d_ws, size_t ws_size,
                              hipStream_t stream) {
    const float* x    = (const float*)d_in[0];
    const int*   edges= (const int*)d_in[1];
    const float* W1   = (const float*)d_in[3];
    const float* b1   = (const float*)d_in[4];
    const float* W2   = (const float*)d_in[5];
    const float* b2   = (const float*)d_in[6];
    const float* Wih0 = (const float*)d_in[7];
    const float* Whh0 = (const float*)d_in[8];
    const float* bih0 = (const float*)d_in[9];
    const float* bhh0 = (const float*)d_in[10];
    const float* Wih1 = (const float*)d_in[11];
    const float* Whh1 = (const float*)d_in[12];
    const float* bih1 = (const float*)d_in[13];
    const float* bhh1 = (const float*)d_in[14];
    const float* Wlin = (const float*)d_in[15];
    const float* blin = (const float*)d_in[16];
    (void)in_sizes; (void)n_in; (void)out_size;

    char* p = (char*)d_ws;
    auto alloc = [&](size_t bytes) -> char* {
        char* q = p; p += (bytes + 255) & ~(size_t)255; return q;
    };
    int*   hist     = (int*)  alloc(sizeof(int)   * T_STEPS * NNODES);
    int*   rowstart = (int*)  alloc(sizeof(int)   * T_STEPS * RS_STRIDE);
    float* dinv     = (float*)alloc(sizeof(float) * T_STEPS * NNODES);
    int*   col      = (int*)  alloc(sizeof(int)   * T_STEPS * NEDGES);
    float* pooled   = (float*)alloc(sizeof(float) * T_STEPS * HG);
    u16*   W1t      = (u16*)  alloc(sizeof(u16)   * HG * FIN);
    u16*   W2t      = (u16*)  alloc(sizeof(u16)   * HG * HG);
    float* pre0     = (float*)alloc(sizeof(float) * T_STEPS * 1024);
    float* hbuf     = (float*)alloc(sizeof(float) * 2 * 256);
    float* hseq_g   = (float*)alloc(sizeof(float) * T_STEPS * 256);
    int*   flags    = (int*)  alloc(sizeof(int)   * 4);
    size_t fixed_used = (size_t)(p - (char*)d_ws);

    const size_t xb_bytes  = sizeof(u16) * (size_t)T_STEPS * NNODES * FIN;
    const size_t per_g     = (size_t)MPAD * HG * 2 * 2;
    const size_t slack     = 4096 * 16;
    static const int gopts[6] = {12, 6, 4, 3, 2, 1};
    int G = 1;
    for (int i = 0; i < 6; ++i)
        if (fixed_used + xb_bytes + per_g * gopts[i] + slack <= ws_size) { G = gopts[i]; break; }
    u16* xb   = (u16*)alloc(xb_bytes);
    u16* h1b  = (u16*)alloc(sizeof(u16) * (size_t)G * MPAD * HG);
    u16* aggu = (u16*)alloc(sizeof(u16) * (size_t)G * MPAD * HG);

    hipMemsetAsync(hist, 0, sizeof(int) * T_STEPS * NNODES, stream);
    hipMemsetAsync(pooled, 0, sizeof(float) * T_STEPS * HG, stream);
    hipMemsetAsync(flags, 0, sizeof(int) * 4, stream);

    int tot = T_STEPS * NEDGES;
    hist_kernel<<<(tot + 255) / 256, 256, 0, stream>>>(edges, hist);
    scan_kernel<<<T_STEPS, 1024, 0, stream>>>(hist, rowstart, dinv);
    fill_kernel<<<(tot + 255) / 256, 256, 0, stream>>>(edges, rowstart, hist, col);
    convw_kernel<<<HG * FIN / 256, 256, 0, stream>>>(W1, W1t, FIN);
    convw_kernel<<<HG * HG  / 256, 256, 0, stream>>>(W2, W2t, HG);
    x2bf_kernel<<<T_STEPS * NNODES * 32 / 256, 256, 0, stream>>>(x, dinv, xb);

    constexpr int NPB = MPAD / 4;
    for (int g = 0; g < T_STEPS / G; ++g) {
        int t0 = g * G;
        const u16*   xbg = xb + (size_t)t0 * NNODES * FIN;
        const int*   rsg = rowstart + (size_t)t0 * RS_STRIDE;
        const int*   clg = col + (size_t)t0 * NEDGES;
        const float* dvg = dinv + (size_t)t0 * NNODES;
        agg_scalar<FIN, 2, false><<<G * 2 * NPB, 256, 0, stream>>>(
                xbg, rsg, clg, dvg, aggu);
        gemm_bf16<FIN, false><<<G * 313, 256, 0, stream>>>(aggu, W1t, b1, dvg,
                h1b, nullptr);
        agg_scalar<HG, 4, true><<<G * 4 * NPB, 256, 0, stream>>>(
                h1b, rsg, clg, dvg, aggu);
        gemm_bf16<HG, true><<<G * 313, 256, 0, stream>>>(aggu, W2t, b2, nullptr,
                nullptr, pooled + (size_t)t0 * HG);
    }
    pre0_kernel<<<8, 128, 0, stream>>>(pooled, Wih0, bih0, bhh0, pre0);
    lstm4<<<4, 256, 0, stream>>>(pre0, Whh0, Wih1, Whh1, bih1, bhh1, Wlin, blin,
                                 hbuf, hseq_g, flags, (float*)d_out);
}

// Round 9
// 1264.849 us; speedup vs baseline: 1.0414x; 1.0414x over previous
//
#include <hip/hip_runtime.h>
#include <hip/hip_bf16.h>
#include <math.h>

#define T_STEPS 12
#define NNODES  20000
#define NEDGES  320000
#define MPAD    20032
#define FIN     128
#define HG      256
#define RS_STRIDE 20032

typedef unsigned short u16;
typedef unsigned int   u32;
using bf16x8 = __attribute__((ext_vector_type(8))) short;
using f32x4  = __attribute__((ext_vector_type(4))) float;

__device__ __forceinline__ float bf2f(u16 u) {
    union { u32 i; float f; } v; v.i = ((u32)u) << 16; return v.f;
}
__device__ __forceinline__ u16 f2bf(float f) {
    union { float f; u32 i; } v; v.f = f;
    u32 r = v.i + 0x7fffu + ((v.i >> 16) & 1u);
    return (u16)(r >> 16);
}
__device__ __forceinline__ u16 f2h(float f) {
    _Float16 h = (_Float16)f; u16 u; __builtin_memcpy(&u, &h, 2); return u;
}
__device__ __forceinline__ float h2f(u16 u) {
    _Float16 h; __builtin_memcpy(&h, &u, 2); return (float)h;
}
__device__ __forceinline__ void gload16(const void* g, void* l) {
    __builtin_amdgcn_global_load_lds(
        (const __attribute__((address_space(1))) u32*)g,
        (__attribute__((address_space(3))) u32*)l, 16, 0, 0);
}
__device__ __forceinline__ float sigm(float x) { return 1.f / (1.f + expf(-x)); }
__device__ __forceinline__ void astore(float* p, float v) {
    __hip_atomic_store(p, v, __ATOMIC_RELAXED, __HIP_MEMORY_SCOPE_AGENT);
}
__device__ __forceinline__ float aload(const float* p) {
    return __hip_atomic_load(p, __ATOMIC_RELAXED, __HIP_MEMORY_SCOPE_AGENT);
}

// ---------------- CSR build (verified R1-R8) ----------------

__global__ void hist_kernel(const int* __restrict__ edges, int* __restrict__ hist) {
    int idx = blockIdx.x * blockDim.x + threadIdx.x;
    if (idx >= T_STEPS * NEDGES) return;
    int t = idx / NEDGES, e = idx - t * NEDGES;
    int d = edges[t * 2 * NEDGES + NEDGES + e];
    atomicAdd(&hist[t * NNODES + d], 1);
}

__global__ void __launch_bounds__(1024) scan_kernel(int* __restrict__ hist,
        int* __restrict__ rowstart, float* __restrict__ dinv) {
    int t = blockIdx.x;
    int tid = threadIdx.x;
    int wid = tid >> 6, lane = tid & 63;
    __shared__ int wsum[16];
    __shared__ int carry_s;
    if (tid == 0) carry_s = 0;
    __syncthreads();
    for (int base = 0; base < NNODES; base += 1024) {
        int i = base + tid;
        int orig = (i < NNODES) ? hist[t * NNODES + i] : 0;
        int v = orig;
#pragma unroll
        for (int off = 1; off < 64; off <<= 1) {
            int n = __shfl_up(v, off);
            if (lane >= off) v += n;
        }
        if (lane == 63) wsum[wid] = v;
        __syncthreads();
        if (wid == 0 && lane < 16) {
            int s = wsum[lane];
#pragma unroll
            for (int off = 1; off < 16; off <<= 1) {
                int n = __shfl_up(s, off);
                if (lane >= off) s += n;
            }
            wsum[lane] = s;
        }
        __syncthreads();
        int incl = v + (wid > 0 ? wsum[wid - 1] : 0) + carry_s;
        int excl = incl - orig;
        if (i < NNODES) {
            rowstart[t * RS_STRIDE + i] = excl;
            dinv[t * NNODES + i] = rsqrtf((float)(orig + 1));
            hist[t * NNODES + i] = 0;
        }
        __syncthreads();
        if (tid == 0) carry_s += wsum[15];
        __syncthreads();
    }
    if (tid == 0) rowstart[t * RS_STRIDE + NNODES] = carry_s;
}

__global__ void fill_kernel(const int* __restrict__ edges, const int* __restrict__ rowstart,
        int* __restrict__ cursor, int* __restrict__ col) {
    int idx = blockIdx.x * blockDim.x + threadIdx.x;
    if (idx >= T_STEPS * NEDGES) return;
    int t = idx / NEDGES, e = idx - t * NEDGES;
    int s = edges[t * 2 * NEDGES + e];
    int d = edges[t * 2 * NEDGES + NEDGES + e];
    int pos = rowstart[t * RS_STRIDE + d] + atomicAdd(&cursor[t * NNODES + d], 1);
    col[t * NEDGES + pos] = s;
}

// ---------------- merged conversions: xb premult, W1t, W2t, zero pooled+flags ----------------
// runs after scan (needs dinv). grid = 30385 x 256.

__global__ void __launch_bounds__(256) convall(
        const float* __restrict__ x, const float* __restrict__ dinv, u16* __restrict__ xb,
        const float* __restrict__ W1, u16* __restrict__ W1t,
        const float* __restrict__ W2, u16* __restrict__ W2t,
        float* __restrict__ pooled, int* __restrict__ flags) {
    int bid = blockIdx.x;
    int tid = threadIdx.x;
    if (bid < 30000) {
        int idx = bid * 256 + tid;
        int row = idx >> 5, q = (idx & 31) << 2;
        float dn = dinv[row];
        float4 v = *(const float4*)&x[(size_t)row * FIN + q];
        ushort4 o;
        o.x = f2bf(dn * v.x); o.y = f2bf(dn * v.y);
        o.z = f2bf(dn * v.z); o.w = f2bf(dn * v.w);
        *(ushort4*)&xb[(size_t)row * FIN + q] = o;
    } else if (bid < 30128) {
        int idx = (bid - 30000) * 256 + tid;      // [256][128]
        int n = idx / FIN, k = idx - n * FIN;
        W1t[idx] = f2bf(W1[k * HG + n]);
    } else if (bid < 30384) {
        int idx = (bid - 30128) * 256 + tid;      // [256][256]
        int n = idx >> 8, k = idx & 255;
        W2t[idx] = f2bf(W2[k * HG + n]);
    } else {
        for (int i = tid; i < T_STEPS * HG; i += 256) pooled[i] = 0.f;
        if (tid < 2) flags[tid] = 0;
    }
}

// ---------------- pull aggregation, R5-verified best (1 node/wave, 16-deep) ----------------
// rows PRE-SCALED by dinv: out[d] = dinv[d]*(row[d] + sum_{s->d} row[s]).

__global__ void __launch_bounds__(256) agg128(const u16* __restrict__ xb,
        const int* __restrict__ rowstart, const int* __restrict__ col,
        const float* __restrict__ dinv, u16* __restrict__ out) {
    int glob = (blockIdx.x << 2) + (threadIdx.x >> 6);
    int lane = threadIdx.x & 63;
    int t = glob / MPAD, node = glob - t * MPAD;
    u16* orow = out + ((size_t)glob) * FIN;
    if (node >= NNODES) { *(u32*)&orow[lane << 1] = 0; return; }
    const u16* xt = xb + (size_t)t * NNODES * FIN;
    const int* cb = col + (size_t)t * NEDGES;
    int o2 = lane << 1;
    u32 pv = *(const u32*)&xt[(size_t)node * FIN + o2];
    float ax = bf2f((u16)pv), ay = bf2f((u16)(pv >> 16));
    int s0 = rowstart[t * RS_STRIDE + node], s1 = rowstart[t * RS_STRIDE + node + 1];
    int e = s0;
    for (; e + 16 <= s1; e += 16) {
        int ix[16]; u32 rv[16];
#pragma unroll
        for (int j = 0; j < 16; ++j) ix[j] = cb[e + j];
#pragma unroll
        for (int j = 0; j < 16; ++j) rv[j] = *(const u32*)&xt[(size_t)ix[j] * FIN + o2];
#pragma unroll
        for (int j = 0; j < 16; ++j) {
            ax += bf2f((u16)rv[j]); ay += bf2f((u16)(rv[j] >> 16));
        }
    }
    for (; e + 4 <= s1; e += 4) {
        int ix[4]; u32 rv[4];
#pragma unroll
        for (int j = 0; j < 4; ++j) ix[j] = cb[e + j];
#pragma unroll
        for (int j = 0; j < 4; ++j) rv[j] = *(const u32*)&xt[(size_t)ix[j] * FIN + o2];
#pragma unroll
        for (int j = 0; j < 4; ++j) {
            ax += bf2f((u16)rv[j]); ay += bf2f((u16)(rv[j] >> 16));
        }
    }
    for (; e < s1; ++e) {
        u32 rv = *(const u32*)&xt[(size_t)cb[e] * FIN + o2];
        ax += bf2f((u16)rv); ay += bf2f((u16)(rv >> 16));
    }
    float dn = dinv[t * NNODES + node];
    u32 packed = (u32)f2bf(dn * ax) | ((u32)f2bf(dn * ay) << 16);
    *(u32*)&orow[o2] = packed;
}

__global__ void __launch_bounds__(256) agg256(const u16* __restrict__ xin,
        const int* __restrict__ rowstart, const int* __restrict__ col,
        const float* __restrict__ dinv, u16* __restrict__ out) {
    int glob = (blockIdx.x << 2) + (threadIdx.x >> 6);
    int lane = threadIdx.x & 63;
    int t = glob / MPAD, node = glob - t * MPAD;
    u16* orow = out + ((size_t)glob) * HG;
    if (node >= NNODES) { *(ushort4*)&orow[lane << 2] = make_ushort4(0, 0, 0, 0); return; }
    const u16* xt = xin + (size_t)t * MPAD * HG;
    const int* cb = col + (size_t)t * NEDGES;
    int o4 = lane << 2;
    ushort4 v = *(const ushort4*)&xt[(size_t)node * HG + o4];
    float a0 = bf2f(v.x), a1 = bf2f(v.y), a2 = bf2f(v.z), a3 = bf2f(v.w);
    int s0 = rowstart[t * RS_STRIDE + node], s1 = rowstart[t * RS_STRIDE + node + 1];
    int e = s0;
    for (; e + 16 <= s1; e += 16) {
        int ix[16]; ushort4 rv[16];
#pragma unroll
        for (int j = 0; j < 16; ++j) ix[j] = cb[e + j];
#pragma unroll
        for (int j = 0; j < 16; ++j) rv[j] = *(const ushort4*)&xt[(size_t)ix[j] * HG + o4];
#pragma unroll
        for (int j = 0; j < 16; ++j) {
            a0 += bf2f(rv[j].x); a1 += bf2f(rv[j].y);
            a2 += bf2f(rv[j].z); a3 += bf2f(rv[j].w);
        }
    }
    for (; e + 4 <= s1; e += 4) {
        int ix[4]; ushort4 rv[4];
#pragma unroll
        for (int j = 0; j < 4; ++j) ix[j] = cb[e + j];
#pragma unroll
        for (int j = 0; j < 4; ++j) rv[j] = *(const ushort4*)&xt[(size_t)ix[j] * HG + o4];
#pragma unroll
        for (int j = 0; j < 4; ++j) {
            a0 += bf2f(rv[j].x); a1 += bf2f(rv[j].y);
            a2 += bf2f(rv[j].z); a3 += bf2f(rv[j].w);
        }
    }
    for (; e < s1; ++e) {
        ushort4 rv = *(const ushort4*)&xt[(size_t)cb[e] * HG + o4];
        a0 += bf2f(rv.x); a1 += bf2f(rv.y); a2 += bf2f(rv.z); a3 += bf2f(rv.w);
    }
    float dn = dinv[t * NNODES + node];
    ushort4 o;
    o.x = f2bf(dn * a0); o.y = f2bf(dn * a1); o.z = f2bf(dn * a2); o.w = f2bf(dn * a3);
    *(ushort4*)&orow[o4] = o;
}

// ---------------- bf16 MFMA GEMM, 64M x 256N tile (verified R7/R8) ----------------

template <int K, bool POOL>
__global__ __launch_bounds__(256) void gemm_bf16(
        const u16* __restrict__ A, const u16* __restrict__ Bt,
        const float* __restrict__ bias, const float* __restrict__ dscale,
        u16* __restrict__ C, float* __restrict__ pool) {
    __shared__ u16 As[64 * 64];      // 8 KB
    __shared__ u16 Bs[256 * 64];     // 32 KB
    __shared__ float csum[HG];
    int tid = threadIdx.x;
    int bm = blockIdx.x * 64;
    int t8 = tid >> 3, sl = tid & 7;
    int lane = tid & 63, w = tid >> 6;
    int r0 = lane & 15, gq = lane >> 4;
    int tblk = blockIdx.x / 313;

    f32x4 acc[4][4] = {};

    for (int k0 = 0; k0 < K; k0 += 64) {
#pragma unroll
        for (int i = 0; i < 2; ++i) {
            int r = i * 32 + t8;
            int ch = sl ^ (r & 7);
            gload16(A + (size_t)(bm + r) * K + k0 + ch * 8, &As[i * 2048 + tid * 8]);
        }
#pragma unroll
        for (int i = 0; i < 8; ++i) {
            int r = i * 32 + t8;
            int ch = sl ^ (r & 7);
            gload16(Bt + (size_t)r * K + k0 + ch * 8, &Bs[i * 2048 + tid * 8]);
        }
        __syncthreads();
#pragma unroll
        for (int kk = 0; kk < 2; ++kk) {
            bf16x8 a[4], b[4];
#pragma unroll
            for (int mi = 0; mi < 4; ++mi) {
                int R = mi * 16 + r0;
                int s = (kk * 4 + gq) ^ (R & 7);
                a[mi] = *(const bf16x8*)&As[R * 64 + s * 8];
            }
#pragma unroll
            for (int ni = 0; ni < 4; ++ni) {
                int R = w * 64 + ni * 16 + r0;
                int s = (kk * 4 + gq) ^ (R & 7);
                b[ni] = *(const bf16x8*)&Bs[R * 64 + s * 8];
            }
#pragma unroll
            for (int mi = 0; mi < 4; ++mi)
#pragma unroll
                for (int ni = 0; ni < 4; ++ni)
                    acc[mi][ni] = __builtin_amdgcn_mfma_f32_16x16x32_bf16(
                        a[mi], b[ni], acc[mi][ni], 0, 0, 0);
        }
        __syncthreads();
    }

    if (!POOL) {
#pragma unroll
        for (int ni = 0; ni < 4; ++ni) {
            int colg = w * 64 + ni * 16 + r0;
            float b = bias[colg];
#pragma unroll
            for (int mi = 0; mi < 4; ++mi) {
                int rbase = bm + mi * 16 + gq * 4;
#pragma unroll
                for (int q = 0; q < 4; ++q) {
                    int row = rbase + q;
                    int rloc = row - tblk * MPAD;
                    float sc = (rloc < NNODES) ? dscale[tblk * NNODES + rloc] : 0.f;
                    C[(size_t)row * HG + colg] = f2bf(sc * fmaxf(acc[mi][ni][q] + b, 0.f));
                }
            }
        }
    } else {
        csum[tid] = 0.f;
        __syncthreads();
#pragma unroll
        for (int ni = 0; ni < 4; ++ni) {
            int colg = w * 64 + ni * 16 + r0;
            float b = bias[colg];
            float s = 0.f;
#pragma unroll
            for (int mi = 0; mi < 4; ++mi) {
                int rbase = bm + mi * 16 + gq * 4;
#pragma unroll
                for (int q = 0; q < 4; ++q) {
                    int row = rbase + q;
                    int rloc = row - tblk * MPAD;
                    if (rloc < NNODES) s += fmaxf(acc[mi][ni][q] + b, 0.f);
                }
            }
            atomicAdd(&csum[colg], s);
        }
        __syncthreads();
        atomicAdd(&pool[tblk * HG + tid], csum[tid]);
    }
}

// ---------------- 2-block cooperative LSTM, 512 thr/block ----------------
// Block b owns hidden units [b*128, b*128+128) -> 512 gate rows, one per thread.
// Whh row (256 fp16) lives in 128 VGPRs. Input projections (fp32 weights) inlined.
// Per-step: 2-party flag handshake (busy spin), h exchange via hbuf (double buffer).

__global__ void __launch_bounds__(512, 1) lstm2b(
        const float* __restrict__ pooled,
        const float* __restrict__ Wih0, const float* __restrict__ bih0,
        const float* __restrict__ bhh0,
        const float* __restrict__ Whh0, const float* __restrict__ Wih1,
        const float* __restrict__ Whh1,
        const float* __restrict__ bih1, const float* __restrict__ bhh1,
        const float* __restrict__ Wlin, const float* __restrict__ blin,
        float* hbuf, int* flags, float* __restrict__ out) {
    __shared__ float xs[T_STEPS][HG];
    __shared__ float hseqL[T_STEPS][HG];
    __shared__ float hl[HG];
    __shared__ float garr[512];
    int tid = threadIdx.x;
    int b = blockIdx.x, ob = 1 - b;
    int gate = tid >> 7, lu = tid & 127;
    int unit = b * 128 + lu;
    int r = gate * 256 + unit;

    for (int i = tid; i < T_STEPS * HG; i += 512)
        ((float*)xs)[i] = pooled[i] * (1.f / (float)NNODES);
    __syncthreads();

    // layer-0 input projection (fp32), bias folded
    float pre[T_STEPS];
    {
        const float4* w4 = (const float4*)(Wih0 + (size_t)r * HG);
#pragma unroll
        for (int t = 0; t < T_STEPS; ++t) pre[t] = 0.f;
        for (int i = 0; i < 64; ++i) {
            float4 wv = w4[i];
#pragma unroll
            for (int t = 0; t < T_STEPS; ++t) {
                float4 xv = *(const float4*)&xs[t][i * 4];
                pre[t] += wv.x * xv.x + wv.y * xv.y + wv.z * xv.z + wv.w * xv.w;
            }
        }
        float bb = bih0[r] + bhh0[r];
#pragma unroll
        for (int t = 0; t < T_STEPS; ++t) pre[t] += bb;
    }

    u32 wreg[128];
    float c = 0.f;
    for (int layer = 0; layer < 2; ++layer) {
        const float* Whh = layer ? Whh1 : Whh0;
        {
            const float4* w4 = (const float4*)(Whh + (size_t)r * HG);
#pragma unroll
            for (int i = 0; i < 64; ++i) {
                float4 v = w4[i];
                wreg[2 * i]     = (u32)f2h(v.x) | ((u32)f2h(v.y) << 16);
                wreg[2 * i + 1] = (u32)f2h(v.z) | ((u32)f2h(v.w) << 16);
            }
        }
        c = 0.f;
        if (tid < HG) hl[tid] = 0.f;
        __syncthreads();
        for (int t = 0; t < T_STEPS; ++t) {
            int s = layer * T_STEPS + t + 1;
            float acc = 0.f;
#pragma unroll
            for (int k2 = 0; k2 < 128; ++k2) {
                u32 wv = wreg[k2];
                float2 hv = *(const float2*)&hl[k2 * 2];
                acc += h2f((u16)wv) * hv.x + h2f((u16)(wv >> 16)) * hv.y;
            }
            garr[tid] = pre[t] + acc;
            __syncthreads();
            if (tid < 128) {
                float ig = sigm(garr[tid]);
                float fg = sigm(garr[128 + tid]);
                float gg = tanhf(garr[256 + tid]);
                float og = sigm(garr[384 + tid]);
                c = fg * c + ig * gg;
                float hn = og * tanhf(c);
                hl[unit] = hn;                       // unit = b*128+tid here
                astore(&hbuf[(s & 1) * 256 + unit], hn);
            }
            __syncthreads();
            if (tid == 0) {
                __hip_atomic_store(&flags[b], s, __ATOMIC_RELEASE,
                                   __HIP_MEMORY_SCOPE_AGENT);
                while (__hip_atomic_load(&flags[ob], __ATOMIC_ACQUIRE,
                                         __HIP_MEMORY_SCOPE_AGENT) < s) {}
            }
            __syncthreads();
            if (tid < 128) hl[ob * 128 + tid] = aload(&hbuf[(s & 1) * 256 + ob * 128 + tid]);
            __syncthreads();
            if (layer == 0 && tid < HG) hseqL[t][tid] = hl[tid];
        }
        if (layer == 0) {
            __syncthreads();
            // layer-1 input projection from hseqL (fp32)
            const float4* w4 = (const float4*)(Wih1 + (size_t)r * HG);
#pragma unroll
            for (int t = 0; t < T_STEPS; ++t) pre[t] = 0.f;
            for (int i = 0; i < 64; ++i) {
                float4 wv = w4[i];
#pragma unroll
                for (int t = 0; t < T_STEPS; ++t) {
                    float4 hv = *(const float4*)&hseqL[t][i * 4];
                    pre[t] += wv.x * hv.x + wv.y * hv.y + wv.z * hv.z + wv.w * hv.w;
                }
            }
            float bb = bih1[r] + bhh1[r];
#pragma unroll
            for (int t = 0; t < T_STEPS; ++t) pre[t] += bb;
        }
    }

    if (b == 0 && tid < 8) {
        float s = blin[tid];
        const float* wl = Wlin + tid * HG;
        for (int k = 0; k < HG; ++k) s += hl[k] * wl[k];
        out[tid] = s;
    }
}

// ---------------- orchestration ----------------

extern "C" void kernel_launch(void* const* d_in, const int* in_sizes, int n_in,
                              void* d_out, int out_size, void* d_ws, size_t ws_size,
                              hipStream_t stream) {
    const float* x    = (const float*)d_in[0];
    const int*   edges= (const int*)d_in[1];
    const float* W1   = (const float*)d_in[3];
    const float* b1   = (const float*)d_in[4];
    const float* W2   = (const float*)d_in[5];
    const float* b2   = (const float*)d_in[6];
    const float* Wih0 = (const float*)d_in[7];
    const float* Whh0 = (const float*)d_in[8];
    const float* bih0 = (const float*)d_in[9];
    const float* bhh0 = (const float*)d_in[10];
    const float* Wih1 = (const float*)d_in[11];
    const float* Whh1 = (const float*)d_in[12];
    const float* bih1 = (const float*)d_in[13];
    const float* bhh1 = (const float*)d_in[14];
    const float* Wlin = (const float*)d_in[15];
    const float* blin = (const float*)d_in[16];
    (void)in_sizes; (void)n_in; (void)out_size;

    char* p = (char*)d_ws;
    auto alloc = [&](size_t bytes) -> char* {
        char* q = p; p += (bytes + 255) & ~(size_t)255; return q;
    };
    int*   hist     = (int*)  alloc(sizeof(int)   * T_STEPS * NNODES);
    int*   rowstart = (int*)  alloc(sizeof(int)   * T_STEPS * RS_STRIDE);
    float* dinv     = (float*)alloc(sizeof(float) * T_STEPS * NNODES);
    int*   col      = (int*)  alloc(sizeof(int)   * T_STEPS * NEDGES);
    float* pooled   = (float*)alloc(sizeof(float) * T_STEPS * HG);
    u16*   W1t      = (u16*)  alloc(sizeof(u16)   * HG * FIN);
    u16*   W2t      = (u16*)  alloc(sizeof(u16)   * HG * HG);
    float* hbuf     = (float*)alloc(sizeof(float) * 2 * 256);
    int*   flags    = (int*)  alloc(sizeof(int)   * 4);
    size_t fixed_used = (size_t)(p - (char*)d_ws);

    const size_t xb_bytes  = sizeof(u16) * (size_t)T_STEPS * NNODES * FIN;
    const size_t per_g     = (size_t)MPAD * HG * 2 * 2;
    const size_t slack     = 4096 * 16;
    static const int gopts[6] = {12, 6, 4, 3, 2, 1};
    int G = 1;
    for (int i = 0; i < 6; ++i)
        if (fixed_used + xb_bytes + per_g * gopts[i] + slack <= ws_size) { G = gopts[i]; break; }
    u16* xb   = (u16*)alloc(xb_bytes);
    u16* h1b  = (u16*)alloc(sizeof(u16) * (size_t)G * MPAD * HG);
    u16* aggu = (u16*)alloc(sizeof(u16) * (size_t)G * MPAD * HG);

    hipMemsetAsync(hist, 0, sizeof(int) * T_STEPS * NNODES, stream);

    int tot = T_STEPS * NEDGES;
    hist_kernel<<<(tot + 255) / 256, 256, 0, stream>>>(edges, hist);
    scan_kernel<<<T_STEPS, 1024, 0, stream>>>(hist, rowstart, dinv);
    fill_kernel<<<(tot + 255) / 256, 256, 0, stream>>>(edges, rowstart, hist, col);
    convall<<<30385, 256, 0, stream>>>(x, dinv, xb, W1, W1t, W2, W2t, pooled, flags);

    for (int g = 0; g < T_STEPS / G; ++g) {
        int t0 = g * G;
        const u16*   xbg = xb + (size_t)t0 * NNODES * FIN;
        const int*   rsg = rowstart + (size_t)t0 * RS_STRIDE;
        const int*   clg = col + (size_t)t0 * NEDGES;
        const float* dvg = dinv + (size_t)t0 * NNODES;
        int nagg = G * MPAD / 4;
        agg128<<<nagg, 256, 0, stream>>>(xbg, rsg, clg, dvg, aggu);
        gemm_bf16<FIN, false><<<G * 313, 256, 0, stream>>>(aggu, W1t, b1, dvg,
                h1b, nullptr);
        agg256<<<nagg, 256, 0, stream>>>(h1b, rsg, clg, dvg, aggu);
        gemm_bf16<HG, true><<<G * 313, 256, 0, stream>>>(aggu, W2t, b2, nullptr,
                nullptr, pooled + (size_t)t0 * HG);
    }
    lstm2b<<<2, 512, 0, stream>>>(pooled, Wih0, bih0, bhh0, Whh0, Wih1, Whh1,
                                  bih1, bhh1, Wlin, blin, hbuf, flags, (float*)d_out);
}

// Round 10
// 1105.332 us; speedup vs baseline: 1.1917x; 1.1443x over previous
//
#include <hip/hip_runtime.h>
#include <hip/hip_bf16.h>
#include <math.h>

#define T_STEPS 12
#define NNODES  20000
#define NEDGES  320000
#define MPAD    20032
#define FIN     128
#define HG      256
#define RS_STRIDE 20032

typedef unsigned short u16;
typedef unsigned int   u32;
typedef unsigned long long u64;
using bf16x8 = __attribute__((ext_vector_type(8))) short;
using f32x4  = __attribute__((ext_vector_type(4))) float;

__device__ __forceinline__ float bf2f(u16 u) {
    union { u32 i; float f; } v; v.i = ((u32)u) << 16; return v.f;
}
__device__ __forceinline__ u16 f2bf(float f) {
    union { float f; u32 i; } v; v.f = f;
    u32 r = v.i + 0x7fffu + ((v.i >> 16) & 1u);
    return (u16)(r >> 16);
}
__device__ __forceinline__ u16 f2h(float f) {
    _Float16 h = (_Float16)f; u16 u; __builtin_memcpy(&u, &h, 2); return u;
}
__device__ __forceinline__ float h2f(u16 u) {
    _Float16 h; __builtin_memcpy(&h, &u, 2); return (float)h;
}
__device__ __forceinline__ void gload16(const void* g, void* l) {
    __builtin_amdgcn_global_load_lds(
        (const __attribute__((address_space(1))) u32*)g,
        (__attribute__((address_space(3))) u32*)l, 16, 0, 0);
}
__device__ __forceinline__ float sigm(float x) { return 1.f / (1.f + expf(-x)); }

// ---------------- CSR build (verified R1-R9) ----------------

__global__ void hist_kernel(const int* __restrict__ edges, int* __restrict__ hist) {
    int idx = blockIdx.x * blockDim.x + threadIdx.x;
    if (idx >= T_STEPS * NEDGES) return;
    int t = idx / NEDGES, e = idx - t * NEDGES;
    int d = edges[t * 2 * NEDGES + NEDGES + e];
    atomicAdd(&hist[t * NNODES + d], 1);
}

__global__ void __launch_bounds__(1024) scan_kernel(int* __restrict__ hist,
        int* __restrict__ rowstart, float* __restrict__ dinv) {
    int t = blockIdx.x;
    int tid = threadIdx.x;
    int wid = tid >> 6, lane = tid & 63;
    __shared__ int wsum[16];
    __shared__ int carry_s;
    if (tid == 0) carry_s = 0;
    __syncthreads();
    for (int base = 0; base < NNODES; base += 1024) {
        int i = base + tid;
        int orig = (i < NNODES) ? hist[t * NNODES + i] : 0;
        int v = orig;
#pragma unroll
        for (int off = 1; off < 64; off <<= 1) {
            int n = __shfl_up(v, off);
            if (lane >= off) v += n;
        }
        if (lane == 63) wsum[wid] = v;
        __syncthreads();
        if (wid == 0 && lane < 16) {
            int s = wsum[lane];
#pragma unroll
            for (int off = 1; off < 16; off <<= 1) {
                int n = __shfl_up(s, off);
                if (lane >= off) s += n;
            }
            wsum[lane] = s;
        }
        __syncthreads();
        int incl = v + (wid > 0 ? wsum[wid - 1] : 0) + carry_s;
        int excl = incl - orig;
        if (i < NNODES) {
            rowstart[t * RS_STRIDE + i] = excl;
            dinv[t * NNODES + i] = rsqrtf((float)(orig + 1));
            hist[t * NNODES + i] = 0;
        }
        __syncthreads();
        if (tid == 0) carry_s += wsum[15];
        __syncthreads();
    }
    if (tid == 0) rowstart[t * RS_STRIDE + NNODES] = carry_s;
}

__global__ void fill_kernel(const int* __restrict__ edges, const int* __restrict__ rowstart,
        int* __restrict__ cursor, int* __restrict__ col) {
    int idx = blockIdx.x * blockDim.x + threadIdx.x;
    if (idx >= T_STEPS * NEDGES) return;
    int t = idx / NEDGES, e = idx - t * NEDGES;
    int s = edges[t * 2 * NEDGES + e];
    int d = edges[t * 2 * NEDGES + NEDGES + e];
    int pos = rowstart[t * RS_STRIDE + d] + atomicAdd(&cursor[t * NNODES + d], 1);
    col[t * NEDGES + pos] = s;
}

// ---------------- merged conversions: xb premult, W1t, W2t, zero pooled+hbuf ----------------

__global__ void __launch_bounds__(256) convall(
        const float* __restrict__ x, const float* __restrict__ dinv, u16* __restrict__ xb,
        const float* __restrict__ W1, u16* __restrict__ W1t,
        const float* __restrict__ W2, u16* __restrict__ W2t,
        float* __restrict__ pooled, u64* __restrict__ hbuf) {
    int bid = blockIdx.x;
    int tid = threadIdx.x;
    if (bid < 30000) {
        int idx = bid * 256 + tid;
        int row = idx >> 5, q = (idx & 31) << 2;
        float dn = dinv[row];
        float4 v = *(const float4*)&x[(size_t)row * FIN + q];
        ushort4 o;
        o.x = f2bf(dn * v.x); o.y = f2bf(dn * v.y);
        o.z = f2bf(dn * v.z); o.w = f2bf(dn * v.w);
        *(ushort4*)&xb[(size_t)row * FIN + q] = o;
    } else if (bid < 30128) {
        int idx = (bid - 30000) * 256 + tid;      // [256][128]
        int n = idx / FIN, k = idx - n * FIN;
        W1t[idx] = f2bf(W1[k * HG + n]);
    } else if (bid < 30384) {
        int idx = (bid - 30128) * 256 + tid;      // [256][256]
        int n = idx >> 8, k = idx & 255;
        W2t[idx] = f2bf(W2[k * HG + n]);
    } else {
        for (int i = tid; i < T_STEPS * HG; i += 256) pooled[i] = 0.f;
        for (int i = tid; i < 512; i += 256) hbuf[i] = 0ull;   // tags=0 < first step 1
    }
}

// ---------------- pull aggregation, R5-verified best (1 node/wave, 16-deep) ----------------

__global__ void __launch_bounds__(256) agg128(const u16* __restrict__ xb,
        const int* __restrict__ rowstart, const int* __restrict__ col,
        const float* __restrict__ dinv, u16* __restrict__ out) {
    int glob = (blockIdx.x << 2) + (threadIdx.x >> 6);
    int lane = threadIdx.x & 63;
    int t = glob / MPAD, node = glob - t * MPAD;
    u16* orow = out + ((size_t)glob) * FIN;
    if (node >= NNODES) { *(u32*)&orow[lane << 1] = 0; return; }
    const u16* xt = xb + (size_t)t * NNODES * FIN;
    const int* cb = col + (size_t)t * NEDGES;
    int o2 = lane << 1;
    u32 pv = *(const u32*)&xt[(size_t)node * FIN + o2];
    float ax = bf2f((u16)pv), ay = bf2f((u16)(pv >> 16));
    int s0 = rowstart[t * RS_STRIDE + node], s1 = rowstart[t * RS_STRIDE + node + 1];
    int e = s0;
    for (; e + 16 <= s1; e += 16) {
        int ix[16]; u32 rv[16];
#pragma unroll
        for (int j = 0; j < 16; ++j) ix[j] = cb[e + j];
#pragma unroll
        for (int j = 0; j < 16; ++j) rv[j] = *(const u32*)&xt[(size_t)ix[j] * FIN + o2];
#pragma unroll
        for (int j = 0; j < 16; ++j) {
            ax += bf2f((u16)rv[j]); ay += bf2f((u16)(rv[j] >> 16));
        }
    }
    for (; e + 4 <= s1; e += 4) {
        int ix[4]; u32 rv[4];
#pragma unroll
        for (int j = 0; j < 4; ++j) ix[j] = cb[e + j];
#pragma unroll
        for (int j = 0; j < 4; ++j) rv[j] = *(const u32*)&xt[(size_t)ix[j] * FIN + o2];
#pragma unroll
        for (int j = 0; j < 4; ++j) {
            ax += bf2f((u16)rv[j]); ay += bf2f((u16)(rv[j] >> 16));
        }
    }
    for (; e < s1; ++e) {
        u32 rv = *(const u32*)&xt[(size_t)cb[e] * FIN + o2];
        ax += bf2f((u16)rv); ay += bf2f((u16)(rv >> 16));
    }
    float dn = dinv[t * NNODES + node];
    u32 packed = (u32)f2bf(dn * ax) | ((u32)f2bf(dn * ay) << 16);
    *(u32*)&orow[o2] = packed;
}

__global__ void __launch_bounds__(256) agg256(const u16* __restrict__ xin,
        const int* __restrict__ rowstart, const int* __restrict__ col,
        const float* __restrict__ dinv, u16* __restrict__ out) {
    int glob = (blockIdx.x << 2) + (threadIdx.x >> 6);
    int lane = threadIdx.x & 63;
    int t = glob / MPAD, node = glob - t * MPAD;
    u16* orow = out + ((size_t)glob) * HG;
    if (node >= NNODES) { *(ushort4*)&orow[lane << 2] = make_ushort4(0, 0, 0, 0); return; }
    const u16* xt = xin + (size_t)t * MPAD * HG;
    const int* cb = col + (size_t)t * NEDGES;
    int o4 = lane << 2;
    ushort4 v = *(const ushort4*)&xt[(size_t)node * HG + o4];
    float a0 = bf2f(v.x), a1 = bf2f(v.y), a2 = bf2f(v.z), a3 = bf2f(v.w);
    int s0 = rowstart[t * RS_STRIDE + node], s1 = rowstart[t * RS_STRIDE + node + 1];
    int e = s0;
    for (; e + 16 <= s1; e += 16) {
        int ix[16]; ushort4 rv[16];
#pragma unroll
        for (int j = 0; j < 16; ++j) ix[j] = cb[e + j];
#pragma unroll
        for (int j = 0; j < 16; ++j) rv[j] = *(const ushort4*)&xt[(size_t)ix[j] * HG + o4];
#pragma unroll
        for (int j = 0; j < 16; ++j) {
            a0 += bf2f(rv[j].x); a1 += bf2f(rv[j].y);
            a2 += bf2f(rv[j].z); a3 += bf2f(rv[j].w);
        }
    }
    for (; e + 4 <= s1; e += 4) {
        int ix[4]; ushort4 rv[4];
#pragma unroll
        for (int j = 0; j < 4; ++j) ix[j] = cb[e + j];
#pragma unroll
        for (int j = 0; j < 4; ++j) rv[j] = *(const ushort4*)&xt[(size_t)ix[j] * HG + o4];
#pragma unroll
        for (int j = 0; j < 4; ++j) {
            a0 += bf2f(rv[j].x); a1 += bf2f(rv[j].y);
            a2 += bf2f(rv[j].z); a3 += bf2f(rv[j].w);
        }
    }
    for (; e < s1; ++e) {
        ushort4 rv = *(const ushort4*)&xt[(size_t)cb[e] * HG + o4];
        a0 += bf2f(rv.x); a1 += bf2f(rv.y); a2 += bf2f(rv.z); a3 += bf2f(rv.w);
    }
    float dn = dinv[t * NNODES + node];
    ushort4 o;
    o.x = f2bf(dn * a0); o.y = f2bf(dn * a1); o.z = f2bf(dn * a2); o.w = f2bf(dn * a3);
    *(ushort4*)&orow[o4] = o;
}

// ---------------- bf16 MFMA GEMM, 64M x 256N tile (verified R7-R9) ----------------

template <int K, bool POOL>
__global__ __launch_bounds__(256) void gemm_bf16(
        const u16* __restrict__ A, const u16* __restrict__ Bt,
        const float* __restrict__ bias, const float* __restrict__ dscale,
        u16* __restrict__ C, float* __restrict__ pool) {
    __shared__ u16 As[64 * 64];      // 8 KB
    __shared__ u16 Bs[256 * 64];     // 32 KB
    __shared__ float csum[HG];
    int tid = threadIdx.x;
    int bm = blockIdx.x * 64;
    int t8 = tid >> 3, sl = tid & 7;
    int lane = tid & 63, w = tid >> 6;
    int r0 = lane & 15, gq = lane >> 4;
    int tblk = blockIdx.x / 313;

    f32x4 acc[4][4] = {};

    for (int k0 = 0; k0 < K; k0 += 64) {
#pragma unroll
        for (int i = 0; i < 2; ++i) {
            int r = i * 32 + t8;
            int ch = sl ^ (r & 7);
            gload16(A + (size_t)(bm + r) * K + k0 + ch * 8, &As[i * 2048 + tid * 8]);
        }
#pragma unroll
        for (int i = 0; i < 8; ++i) {
            int r = i * 32 + t8;
            int ch = sl ^ (r & 7);
            gload16(Bt + (size_t)r * K + k0 + ch * 8, &Bs[i * 2048 + tid * 8]);
        }
        __syncthreads();
#pragma unroll
        for (int kk = 0; kk < 2; ++kk) {
            bf16x8 a[4], b[4];
#pragma unroll
            for (int mi = 0; mi < 4; ++mi) {
                int R = mi * 16 + r0;
                int s = (kk * 4 + gq) ^ (R & 7);
                a[mi] = *(const bf16x8*)&As[R * 64 + s * 8];
            }
#pragma unroll
            for (int ni = 0; ni < 4; ++ni) {
                int R = w * 64 + ni * 16 + r0;
                int s = (kk * 4 + gq) ^ (R & 7);
                b[ni] = *(const bf16x8*)&Bs[R * 64 + s * 8];
            }
#pragma unroll
            for (int mi = 0; mi < 4; ++mi)
#pragma unroll
                for (int ni = 0; ni < 4; ++ni)
                    acc[mi][ni] = __builtin_amdgcn_mfma_f32_16x16x32_bf16(
                        a[mi], b[ni], acc[mi][ni], 0, 0, 0);
        }
        __syncthreads();
    }

    if (!POOL) {
#pragma unroll
        for (int ni = 0; ni < 4; ++ni) {
            int colg = w * 64 + ni * 16 + r0;
            float b = bias[colg];
#pragma unroll
            for (int mi = 0; mi < 4; ++mi) {
                int rbase = bm + mi * 16 + gq * 4;
#pragma unroll
                for (int q = 0; q < 4; ++q) {
                    int row = rbase + q;
                    int rloc = row - tblk * MPAD;
                    float sc = (rloc < NNODES) ? dscale[tblk * NNODES + rloc] : 0.f;
                    C[(size_t)row * HG + colg] = f2bf(sc * fmaxf(acc[mi][ni][q] + b, 0.f));
                }
            }
        }
    } else {
        csum[tid] = 0.f;
        __syncthreads();
#pragma unroll
        for (int ni = 0; ni < 4; ++ni) {
            int colg = w * 64 + ni * 16 + r0;
            float b = bias[colg];
            float s = 0.f;
#pragma unroll
            for (int mi = 0; mi < 4; ++mi) {
                int rbase = bm + mi * 16 + gq * 4;
#pragma unroll
                for (int q = 0; q < 4; ++q) {
                    int row = rbase + q;
                    int rloc = row - tblk * MPAD;
                    if (rloc < NNODES) s += fmaxf(acc[mi][ni][q] + b, 0.f);
                }
            }
            atomicAdd(&csum[colg], s);
        }
        __syncthreads();
        atomicAdd(&pool[tblk * HG + tid], csum[tid]);
    }
}

// ---------------- 4-block cooperative LSTM, tagged-payload sync (no fences) ----------------
// Block b owns 64 hidden units (b*64..b*64+63) -> 256 gate rows, one per thread.
// Whh row (256 fp16) in 128 VGPRs (launch_bounds(256,1) -> 512-VGPR cap, no spill).
// Per-step h exchange: u64 relaxed AGENT atomics carrying (step_tag<<32)|float_bits.
// Reader spins until tag==step; no acquire/release fences needed (payload is the token).
// Lockstep proof: block reaches step s+1 only after seeing ALL tags==s, and a tag s is
// written by a block only after it consumed step s-1 -> the parity slot being
// overwritten at s+1 (holding s-1) has been consumed by every block. No race.

__global__ void __launch_bounds__(256, 1) lstm4c(
        const float* __restrict__ pooled,
        const float* __restrict__ Wih0, const float* __restrict__ bih0,
        const float* __restrict__ bhh0,
        const float* __restrict__ Whh0, const float* __restrict__ Wih1,
        const float* __restrict__ Whh1,
        const float* __restrict__ bih1, const float* __restrict__ bhh1,
        const float* __restrict__ Wlin, const float* __restrict__ blin,
        u64* hbuf, float* __restrict__ out) {
    __shared__ float xs[T_STEPS][HG];
    __shared__ float hseqL[T_STEPS][HG];
    __shared__ float hl[HG];
    __shared__ float garr[256];
    int tid = threadIdx.x;
    int b = blockIdx.x;
    int lu = tid & 63;
    int unit = b * 64 + lu;
    int r = (tid >> 6) * 256 + unit;

    for (int i = tid; i < T_STEPS * HG; i += 256)
        ((float*)xs)[i] = pooled[i] * (1.f / (float)NNODES);
    __syncthreads();

    // layer-0 input projection (fp32), bias folded
    float pre[T_STEPS];
    {
        const float4* w4 = (const float4*)(Wih0 + (size_t)r * HG);
#pragma unroll
        for (int t = 0; t < T_STEPS; ++t) pre[t] = 0.f;
        for (int i = 0; i < 64; ++i) {
            float4 wv = w4[i];
#pragma unroll
            for (int t = 0; t < T_STEPS; ++t) {
                float4 xv = *(const float4*)&xs[t][i * 4];
                pre[t] += wv.x * xv.x + wv.y * xv.y + wv.z * xv.z + wv.w * xv.w;
            }
        }
        float bb = bih0[r] + bhh0[r];
#pragma unroll
        for (int t = 0; t < T_STEPS; ++t) pre[t] += bb;
    }

    u32 wreg[128];
    for (int layer = 0; layer < 2; ++layer) {
        const float* Whh = layer ? Whh1 : Whh0;
        {
            const float4* w4 = (const float4*)(Whh + (size_t)r * HG);
#pragma unroll
            for (int i = 0; i < 64; ++i) {
                float4 v = w4[i];
                wreg[2 * i]     = (u32)f2h(v.x) | ((u32)f2h(v.y) << 16);
                wreg[2 * i + 1] = (u32)f2h(v.z) | ((u32)f2h(v.w) << 16);
            }
        }
        float c = 0.f;
        hl[tid] = 0.f;
        __syncthreads();
        for (int t = 0; t < T_STEPS; ++t) {
            int s = layer * T_STEPS + t + 1;
            float acc = 0.f;
#pragma unroll
            for (int k2 = 0; k2 < 128; ++k2) {
                u32 wv = wreg[k2];
                float2 hv = *(const float2*)&hl[k2 * 2];
                acc += h2f((u16)wv) * hv.x + h2f((u16)(wv >> 16)) * hv.y;
            }
            garr[tid] = pre[t] + acc;
            __syncthreads();                       // A: garr ready, hl reads done
            if (tid < 64) {
                float ig = sigm(garr[lu]);
                float fg = sigm(garr[64 + lu]);
                float gg = tanhf(garr[128 + lu]);
                float og = sigm(garr[192 + lu]);
                c = fg * c + ig * gg;
                float hn = og * tanhf(c);
                u32 hb; __builtin_memcpy(&hb, &hn, 4);
                u64 pk = ((u64)(u32)s << 32) | (u64)hb;
                __hip_atomic_store(&hbuf[(s & 1) * 256 + unit], pk,
                                   __ATOMIC_RELAXED, __HIP_MEMORY_SCOPE_AGENT);
            }
            u64 v;
            do {
                v = __hip_atomic_load(&hbuf[(s & 1) * 256 + tid],
                                      __ATOMIC_RELAXED, __HIP_MEMORY_SCOPE_AGENT);
            } while ((u32)(v >> 32) != (u32)s);
            u32 lo = (u32)v;
            float hv; __builtin_memcpy(&hv, &lo, 4);
            __syncthreads();                       // B: garr reads done, spins done
            hl[tid] = hv;
            if (layer == 0) hseqL[t][tid] = hv;
            __syncthreads();                       // C: hl ready for next step
        }
        if (layer == 0) {
            // layer-1 input projection from hseqL (fp32)
            const float4* w4 = (const float4*)(Wih1 + (size_t)r * HG);
#pragma unroll
            for (int t = 0; t < T_STEPS; ++t) pre[t] = 0.f;
            for (int i = 0; i < 64; ++i) {
                float4 wv = w4[i];
#pragma unroll
                for (int t = 0; t < T_STEPS; ++t) {
                    float4 hv = *(const float4*)&hseqL[t][i * 4];
                    pre[t] += wv.x * hv.x + wv.y * hv.y + wv.z * hv.z + wv.w * hv.w;
                }
            }
            float bb = bih1[r] + bhh1[r];
#pragma unroll
            for (int t = 0; t < T_STEPS; ++t) pre[t] += bb;
            __syncthreads();
        }
    }

    if (b == 0 && tid < 8) {
        float s = blin[tid];
        const float* wl = Wlin + tid * HG;
        for (int k = 0; k < HG; ++k) s += hl[k] * wl[k];
        out[tid] = s;
    }
}

// ---------------- orchestration ----------------

extern "C" void kernel_launch(void* const* d_in, const int* in_sizes, int n_in,
                              void* d_out, int out_size, void* d_ws, size_t ws_size,
                              hipStream_t stream) {
    const float* x    = (const float*)d_in[0];
    const int*   edges= (const int*)d_in[1];
    const float* W1   = (const float*)d_in[3];
    const float* b1   = (const float*)d_in[4];
    const float* W2   = (const float*)d_in[5];
    const float* b2   = (const float*)d_in[6];
    const float* Wih0 = (const float*)d_in[7];
    const float* Whh0 = (const float*)d_in[8];
    const float* bih0 = (const float*)d_in[9];
    const float* bhh0 = (const float*)d_in[10];
    const float* Wih1 = (const float*)d_in[11];
    const float* Whh1 = (const float*)d_in[12];
    const float* bih1 = (const float*)d_in[13];
    const float* bhh1 = (const float*)d_in[14];
    const float* Wlin = (const float*)d_in[15];
    const float* blin = (const float*)d_in[16];
    (void)in_sizes; (void)n_in; (void)out_size;

    char* p = (char*)d_ws;
    auto alloc = [&](size_t bytes) -> char* {
        char* q = p; p += (bytes + 255) & ~(size_t)255; return q;
    };
    int*   hist     = (int*)  alloc(sizeof(int)   * T_STEPS * NNODES);
    int*   rowstart = (int*)  alloc(sizeof(int)   * T_STEPS * RS_STRIDE);
    float* dinv     = (float*)alloc(sizeof(float) * T_STEPS * NNODES);
    int*   col      = (int*)  alloc(sizeof(int)   * T_STEPS * NEDGES);
    float* pooled   = (float*)alloc(sizeof(float) * T_STEPS * HG);
    u16*   W1t      = (u16*)  alloc(sizeof(u16)   * HG * FIN);
    u16*   W2t      = (u16*)  alloc(sizeof(u16)   * HG * HG);
    u64*   hbuf     = (u64*)  alloc(sizeof(u64)   * 2 * 256);
    size_t fixed_used = (size_t)(p - (char*)d_ws);

    const size_t xb_bytes  = sizeof(u16) * (size_t)T_STEPS * NNODES * FIN;
    const size_t per_g     = (size_t)MPAD * HG * 2 * 2;
    const size_t slack     = 4096 * 16;
    static const int gopts[6] = {12, 6, 4, 3, 2, 1};
    int G = 1;
    for (int i = 0; i < 6; ++i)
        if (fixed_used + xb_bytes + per_g * gopts[i] + slack <= ws_size) { G = gopts[i]; break; }
    u16* xb   = (u16*)alloc(xb_bytes);
    u16* h1b  = (u16*)alloc(sizeof(u16) * (size_t)G * MPAD * HG);
    u16* aggu = (u16*)alloc(sizeof(u16) * (size_t)G * MPAD * HG);

    hipMemsetAsync(hist, 0, sizeof(int) * T_STEPS * NNODES, stream);

    int tot = T_STEPS * NEDGES;
    hist_kernel<<<(tot + 255) / 256, 256, 0, stream>>>(edges, hist);
    scan_kernel<<<T_STEPS, 1024, 0, stream>>>(hist, rowstart, dinv);
    fill_kernel<<<(tot + 255) / 256, 256, 0, stream>>>(edges, rowstart, hist, col);
    convall<<<30385, 256, 0, stream>>>(x, dinv, xb, W1, W1t, W2, W2t, pooled, hbuf);

    for (int g = 0; g < T_STEPS / G; ++g) {
        int t0 = g * G;
        const u16*   xbg = xb + (size_t)t0 * NNODES * FIN;
        const int*   rsg = rowstart + (size_t)t0 * RS_STRIDE;
        const int*   clg = col + (size_t)t0 * NEDGES;
        const float* dvg = dinv + (size_t)t0 * NNODES;
        int nagg = G * MPAD / 4;
        agg128<<<nagg, 256, 0, stream>>>(xbg, rsg, clg, dvg, aggu);
        gemm_bf16<FIN, false><<<G * 313, 256, 0, stream>>>(aggu, W1t, b1, dvg,
                h1b, nullptr);
        agg256<<<nagg, 256, 0, stream>>>(h1b, rsg, clg, dvg, aggu);
        gemm_bf16<HG, true><<<G * 313, 256, 0, stream>>>(aggu, W2t, b2, nullptr,
                nullptr, pooled + (size_t)t0 * HG);
    }
    lstm4c<<<4, 256, 0, stream>>>(pooled, Wih0, bih0, bhh0, Whh0, Wih1, Whh1,
                                  bih1, bhh1, Wlin, blin, hbuf, (float*)d_out);
}

// Round 12
// 964.375 us; speedup vs baseline: 1.3659x; 1.1462x over previous
//
#include <hip/hip_runtime.h>
#include <hip/hip_bf16.h>
#include <math.h>

#define T_STEPS 12
#define NNODES  20000
#define NEDGES  320000
#define MPAD    20032
#define FIN     128
#define HG      256
#define RS_STRIDE 20032

typedef unsigned short u16;
typedef unsigned int   u32;
typedef unsigned char  u8;
typedef unsigned long long u64;
using bf16x8 = __attribute__((ext_vector_type(8))) short;
using f32x4  = __attribute__((ext_vector_type(4))) float;
typedef float v2f __attribute__((ext_vector_type(2)));

__device__ __forceinline__ float bf2f(u16 u) {
    union { u32 i; float f; } v; v.i = ((u32)u) << 16; return v.f;
}
__device__ __forceinline__ u16 f2bf(float f) {
    union { float f; u32 i; } v; v.f = f;
    u32 r = v.i + 0x7fffu + ((v.i >> 16) & 1u);
    return (u16)(r >> 16);
}
__device__ __forceinline__ u16 f2h(float f) {
    _Float16 h = (_Float16)f; u16 u; __builtin_memcpy(&u, &h, 2); return u;
}
__device__ __forceinline__ float h2f(u16 u) {
    _Float16 h; __builtin_memcpy(&h, &u, 2); return (float)h;
}
__device__ __forceinline__ void gload16(const void* g, void* l) {
    __builtin_amdgcn_global_load_lds(
        (const __attribute__((address_space(1))) u32*)g,
        (__attribute__((address_space(3))) u32*)l, 16, 0, 0);
}
__device__ __forceinline__ float sigm(float x) { return 1.f / (1.f + expf(-x)); }

// ---------------- CSR build (verified R1-R10) ----------------

__global__ void hist_kernel(const int* __restrict__ edges, int* __restrict__ hist) {
    int idx = blockIdx.x * blockDim.x + threadIdx.x;
    if (idx >= T_STEPS * NEDGES) return;
    int t = idx / NEDGES, e = idx - t * NEDGES;
    int d = edges[t * 2 * NEDGES + NEDGES + e];
    atomicAdd(&hist[t * NNODES + d], 1);
}

__global__ void __launch_bounds__(1024) scan_kernel(int* __restrict__ hist,
        int* __restrict__ rowstart, float* __restrict__ dinv) {
    int t = blockIdx.x;
    int tid = threadIdx.x;
    int wid = tid >> 6, lane = tid & 63;
    __shared__ int wsum[16];
    __shared__ int carry_s;
    if (tid == 0) carry_s = 0;
    __syncthreads();
    for (int base = 0; base < NNODES; base += 1024) {
        int i = base + tid;
        int orig = (i < NNODES) ? hist[t * NNODES + i] : 0;
        int v = orig;
#pragma unroll
        for (int off = 1; off < 64; off <<= 1) {
            int n = __shfl_up(v, off);
            if (lane >= off) v += n;
        }
        if (lane == 63) wsum[wid] = v;
        __syncthreads();
        if (wid == 0 && lane < 16) {
            int s = wsum[lane];
#pragma unroll
            for (int off = 1; off < 16; off <<= 1) {
                int n = __shfl_up(s, off);
                if (lane >= off) s += n;
            }
            wsum[lane] = s;
        }
        __syncthreads();
        int incl = v + (wid > 0 ? wsum[wid - 1] : 0) + carry_s;
        int excl = incl - orig;
        if (i < NNODES) {
            rowstart[t * RS_STRIDE + i] = excl;
            dinv[t * NNODES + i] = rsqrtf((float)(orig + 1));
            hist[t * NNODES + i] = 0;
        }
        __syncthreads();
        if (tid == 0) carry_s += wsum[15];
        __syncthreads();
    }
    if (tid == 0) rowstart[t * RS_STRIDE + NNODES] = carry_s;
}

__global__ void fill_kernel(const int* __restrict__ edges, const int* __restrict__ rowstart,
        int* __restrict__ cursor, int* __restrict__ col) {
    int idx = blockIdx.x * blockDim.x + threadIdx.x;
    if (idx >= T_STEPS * NEDGES) return;
    int t = idx / NEDGES, e = idx - t * NEDGES;
    int s = edges[t * 2 * NEDGES + e];
    int d = edges[t * 2 * NEDGES + NEDGES + e];
    int pos = rowstart[t * RS_STRIDE + d] + atomicAdd(&cursor[t * NNODES + d], 1);
    col[t * NEDGES + pos] = s;
}

// ---------------- merged conversions: xb fp8 premult, W1t, W2t, zero pooled+hbuf ----------------

__global__ void __launch_bounds__(256) convall(
        const float* __restrict__ x, const float* __restrict__ dinv, u8* __restrict__ xb,
        const float* __restrict__ W1, u16* __restrict__ W1t,
        const float* __restrict__ W2, u16* __restrict__ W2t,
        float* __restrict__ pooled, u64* __restrict__ hbuf) {
    int bid = blockIdx.x;
    int tid = threadIdx.x;
    if (bid < 30000) {
        int idx = bid * 256 + tid;
        int row = idx >> 5, q = idx & 31;              // 32 quads of 4 elems per row
        float dn = dinv[row];
        float4 v = *(const float4*)&x[(size_t)row * FIN + q * 4];
        int p = __builtin_amdgcn_cvt_pk_fp8_f32(dn * v.x, dn * v.y, 0, false);
        p = __builtin_amdgcn_cvt_pk_fp8_f32(dn * v.z, dn * v.w, p, true);
        ((u32*)xb)[(size_t)row * 32 + q] = (u32)p;
    } else if (bid < 30128) {
        int idx = (bid - 30000) * 256 + tid;      // [256][128]
        int n = idx / FIN, k = idx - n * FIN;
        W1t[idx] = f2bf(W1[k * HG + n]);
    } else if (bid < 30384) {
        int idx = (bid - 30128) * 256 + tid;      // [256][256]
        int n = idx >> 8, k = idx & 255;
        W2t[idx] = f2bf(W2[k * HG + n]);
    } else {
        for (int i = tid; i < T_STEPS * HG; i += 256) pooled[i] = 0.f;
        for (int i = tid; i < 512; i += 256) hbuf[i] = 0ull;   // tags=0 < first step 1
    }
}

// ---------------- pull aggregation, fp8 payload (R5 structure: 1 node/wave, 16-deep) ----------------
// payload rows PRE-SCALED by dinv and stored fp8 e4m3; accumulate f32; output bf16.
// out[d] = dinv[d]*(row[d] + sum_{s->d} row[s]).

__global__ void __launch_bounds__(256) agg128(const u8* __restrict__ xb,
        const int* __restrict__ rowstart, const int* __restrict__ col,
        const float* __restrict__ dinv, u16* __restrict__ out) {
    int glob = (blockIdx.x << 2) + (threadIdx.x >> 6);
    int lane = threadIdx.x & 63;
    int t = glob / MPAD, node = glob - t * MPAD;
    u16* orow = out + ((size_t)glob) * FIN;
    if (node >= NNODES) { *(u32*)&orow[lane << 1] = 0; return; }
    const u8* xt = xb + (size_t)t * NNODES * FIN;    // fp8 rows, 128 B each
    const int* cb = col + (size_t)t * NEDGES;
    int o2 = lane << 1;
    u32 pv = *(const u16*)&xt[(size_t)node * FIN + o2];
    v2f f = __builtin_amdgcn_cvt_pk_f32_fp8((int)pv, false);
    float ax = f[0], ay = f[1];
    int s0 = rowstart[t * RS_STRIDE + node], s1 = rowstart[t * RS_STRIDE + node + 1];
    int e = s0;
    for (; e + 16 <= s1; e += 16) {
        int ix[16]; u32 rv[16];
#pragma unroll
        for (int j = 0; j < 16; ++j) ix[j] = cb[e + j];
#pragma unroll
        for (int j = 0; j < 16; ++j) rv[j] = *(const u16*)&xt[(size_t)ix[j] * FIN + o2];
#pragma unroll
        for (int j = 0; j < 16; ++j) {
            v2f g = __builtin_amdgcn_cvt_pk_f32_fp8((int)rv[j], false);
            ax += g[0]; ay += g[1];
        }
    }
    for (; e + 4 <= s1; e += 4) {
        int ix[4]; u32 rv[4];
#pragma unroll
        for (int j = 0; j < 4; ++j) ix[j] = cb[e + j];
#pragma unroll
        for (int j = 0; j < 4; ++j) rv[j] = *(const u16*)&xt[(size_t)ix[j] * FIN + o2];
#pragma unroll
        for (int j = 0; j < 4; ++j) {
            v2f g = __builtin_amdgcn_cvt_pk_f32_fp8((int)rv[j], false);
            ax += g[0]; ay += g[1];
        }
    }
    for (; e < s1; ++e) {
        u32 rv = *(const u16*)&xt[(size_t)cb[e] * FIN + o2];
        v2f g = __builtin_amdgcn_cvt_pk_f32_fp8((int)rv, false);
        ax += g[0]; ay += g[1];
    }
    float dn = dinv[t * NNODES + node];
    u32 packed = (u32)f2bf(dn * ax) | ((u32)f2bf(dn * ay) << 16);
    *(u32*)&orow[o2] = packed;
}

__global__ void __launch_bounds__(256) agg256(const u8* __restrict__ xin,
        const int* __restrict__ rowstart, const int* __restrict__ col,
        const float* __restrict__ dinv, u16* __restrict__ out) {
    int glob = (blockIdx.x << 2) + (threadIdx.x >> 6);
    int lane = threadIdx.x & 63;
    int t = glob / MPAD, node = glob - t * MPAD;
    u16* orow = out + ((size_t)glob) * HG;
    if (node >= NNODES) { *(ushort4*)&orow[lane << 2] = make_ushort4(0, 0, 0, 0); return; }
    const u8* xt = xin + (size_t)t * MPAD * HG;      // fp8 rows, 256 B each
    const int* cb = col + (size_t)t * NEDGES;
    int o4 = lane << 2;
    u32 pv = *(const u32*)&xt[(size_t)node * HG + o4];
    v2f f01 = __builtin_amdgcn_cvt_pk_f32_fp8((int)pv, false);
    v2f f23 = __builtin_amdgcn_cvt_pk_f32_fp8((int)pv, true);
    float a0 = f01[0], a1 = f01[1], a2 = f23[0], a3 = f23[1];
    int s0 = rowstart[t * RS_STRIDE + node], s1 = rowstart[t * RS_STRIDE + node + 1];
    int e = s0;
    for (; e + 16 <= s1; e += 16) {
        int ix[16]; u32 rv[16];
#pragma unroll
        for (int j = 0; j < 16; ++j) ix[j] = cb[e + j];
#pragma unroll
        for (int j = 0; j < 16; ++j) rv[j] = *(const u32*)&xt[(size_t)ix[j] * HG + o4];
#pragma unroll
        for (int j = 0; j < 16; ++j) {
            v2f g01 = __builtin_amdgcn_cvt_pk_f32_fp8((int)rv[j], false);
            v2f g23 = __builtin_amdgcn_cvt_pk_f32_fp8((int)rv[j], true);
            a0 += g01[0]; a1 += g01[1]; a2 += g23[0]; a3 += g23[1];
        }
    }
    for (; e + 4 <= s1; e += 4) {
        int ix[4]; u32 rv[4];
#pragma unroll
        for (int j = 0; j < 4; ++j) ix[j] = cb[e + j];
#pragma unroll
        for (int j = 0; j < 4; ++j) rv[j] = *(const u32*)&xt[(size_t)ix[j] * HG + o4];
#pragma unroll
        for (int j = 0; j < 4; ++j) {
            v2f g01 = __builtin_amdgcn_cvt_pk_f32_fp8((int)rv[j], false);
            v2f g23 = __builtin_amdgcn_cvt_pk_f32_fp8((int)rv[j], true);
            a0 += g01[0]; a1 += g01[1]; a2 += g23[0]; a3 += g23[1];
        }
    }
    for (; e < s1; ++e) {
        u32 rv = *(const u32*)&xt[(size_t)cb[e] * HG + o4];
        v2f g01 = __builtin_amdgcn_cvt_pk_f32_fp8((int)rv, false);
        v2f g23 = __builtin_amdgcn_cvt_pk_f32_fp8((int)rv, true);
        a0 += g01[0]; a1 += g01[1]; a2 += g23[0]; a3 += g23[1];
    }
    float dn = dinv[t * NNODES + node];
    ushort4 o;
    o.x = f2bf(dn * a0); o.y = f2bf(dn * a1); o.z = f2bf(dn * a2); o.w = f2bf(dn * a3);
    *(ushort4*)&orow[o4] = o;
}

// ---------------- bf16 MFMA GEMM, 64M x 256N tile (verified R7-R10) ----------------
// !POOL: C[row] = fp8( dscale[row]*relu(acc+bias) ); POOL: per-t column sums.

template <int K, bool POOL>
__global__ __launch_bounds__(256) void gemm_bf16(
        const u16* __restrict__ A, const u16* __restrict__ Bt,
        const float* __restrict__ bias, const float* __restrict__ dscale,
        u8* __restrict__ C, float* __restrict__ pool) {
    __shared__ u16 As[64 * 64];      // 8 KB
    __shared__ u16 Bs[256 * 64];     // 32 KB
    __shared__ float csum[HG];
    int tid = threadIdx.x;
    int bm = blockIdx.x * 64;
    int t8 = tid >> 3, sl = tid & 7;
    int lane = tid & 63, w = tid >> 6;
    int r0 = lane & 15, gq = lane >> 4;
    int tblk = blockIdx.x / 313;

    f32x4 acc[4][4] = {};

    for (int k0 = 0; k0 < K; k0 += 64) {
#pragma unroll
        for (int i = 0; i < 2; ++i) {
            int r = i * 32 + t8;
            int ch = sl ^ (r & 7);
            gload16(A + (size_t)(bm + r) * K + k0 + ch * 8, &As[i * 2048 + tid * 8]);
        }
#pragma unroll
        for (int i = 0; i < 8; ++i) {
            int r = i * 32 + t8;
            int ch = sl ^ (r & 7);
            gload16(Bt + (size_t)r * K + k0 + ch * 8, &Bs[i * 2048 + tid * 8]);
        }
        __syncthreads();
#pragma unroll
        for (int kk = 0; kk < 2; ++kk) {
            bf16x8 a[4], b[4];
#pragma unroll
            for (int mi = 0; mi < 4; ++mi) {
                int R = mi * 16 + r0;
                int s = (kk * 4 + gq) ^ (R & 7);
                a[mi] = *(const bf16x8*)&As[R * 64 + s * 8];
            }
#pragma unroll
            for (int ni = 0; ni < 4; ++ni) {
                int R = w * 64 + ni * 16 + r0;
                int s = (kk * 4 + gq) ^ (R & 7);
                b[ni] = *(const bf16x8*)&Bs[R * 64 + s * 8];
            }
#pragma unroll
            for (int mi = 0; mi < 4; ++mi)
#pragma unroll
                for (int ni = 0; ni < 4; ++ni)
                    acc[mi][ni] = __builtin_amdgcn_mfma_f32_16x16x32_bf16(
                        a[mi], b[ni], acc[mi][ni], 0, 0, 0);
        }
        __syncthreads();
    }

    if (!POOL) {
#pragma unroll
        for (int ni = 0; ni < 4; ++ni) {
            int colg = w * 64 + ni * 16 + r0;
            float b = bias[colg];
#pragma unroll
            for (int mi = 0; mi < 4; ++mi) {
                int rbase = bm + mi * 16 + gq * 4;
#pragma unroll
                for (int q = 0; q < 4; ++q) {
                    int row = rbase + q;
                    int rloc = row - tblk * MPAD;
                    float sc = (rloc < NNODES) ? dscale[tblk * NNODES + rloc] : 0.f;
                    float val = sc * fmaxf(acc[mi][ni][q] + b, 0.f);
                    int p = __builtin_amdgcn_cvt_pk_fp8_f32(val, val, 0, false);
                    C[(size_t)row * HG + colg] = (u8)(p & 0xff);
                }
            }
        }
    } else {
        csum[tid] = 0.f;
        __syncthreads();
#pragma unroll
        for (int ni = 0; ni < 4; ++ni) {
            int colg = w * 64 + ni * 16 + r0;
            float b = bias[colg];
            float s = 0.f;
#pragma unroll
            for (int mi = 0; mi < 4; ++mi) {
                int rbase = bm + mi * 16 + gq * 4;
#pragma unroll
                for (int q = 0; q < 4; ++q) {
                    int row = rbase + q;
                    int rloc = row - tblk * MPAD;
                    if (rloc < NNODES) s += fmaxf(acc[mi][ni][q] + b, 0.f);
                }
            }
            atomicAdd(&csum[colg], s);
        }
        __syncthreads();
        atomicAdd(&pool[tblk * HG + tid], csum[tid]);
    }
}

// ---------------- 4-block cooperative LSTM, tagged-payload sync, SAME-XCD placement ----------------
// grid = 25 blocks; only bid % 8 == 0 (bids 0,8,16,24) are workers -> with round-robin
// block->XCD mapping all 4 workers land on XCD 0, so the per-step h exchange stays in
// one L2. Sync protocol unchanged from R10 (tagged u64 relaxed atomics, proven).

__global__ void __launch_bounds__(256, 1) lstm4c(
        const float* __restrict__ pooled,
        const float* __restrict__ Wih0, const float* __restrict__ bih0,
        const float* __restrict__ bhh0,
        const float* __restrict__ Whh0, const float* __restrict__ Wih1,
        const float* __restrict__ Whh1,
        const float* __restrict__ bih1, const float* __restrict__ bhh1,
        const float* __restrict__ Wlin, const float* __restrict__ blin,
        u64* hbuf, float* __restrict__ out) {
    if (blockIdx.x & 7) return;                    // workers: 0,8,16,24 -> same XCD
    __shared__ float xs[T_STEPS][HG];
    __shared__ float hseqL[T_STEPS][HG];
    __shared__ float hl[HG];
    __shared__ float garr[256];
    int tid = threadIdx.x;
    int b = blockIdx.x >> 3;
    int lu = tid & 63;
    int unit = b * 64 + lu;
    int r = (tid >> 6) * 256 + unit;

    for (int i = tid; i < T_STEPS * HG; i += 256)
        ((float*)xs)[i] = pooled[i] * (1.f / (float)NNODES);
    __syncthreads();

    float pre[T_STEPS];
    {
        const float4* w4 = (const float4*)(Wih0 + (size_t)r * HG);
#pragma unroll
        for (int t = 0; t < T_STEPS; ++t) pre[t] = 0.f;
        for (int i = 0; i < 64; ++i) {
            float4 wv = w4[i];
#pragma unroll
            for (int t = 0; t < T_STEPS; ++t) {
                float4 xv = *(const float4*)&xs[t][i * 4];
                pre[t] += wv.x * xv.x + wv.y * xv.y + wv.z * xv.z + wv.w * xv.w;
            }
        }
        float bb = bih0[r] + bhh0[r];
#pragma unroll
        for (int t = 0; t < T_STEPS; ++t) pre[t] += bb;
    }

    u32 wreg[128];
    for (int layer = 0; layer < 2; ++layer) {
        const float* Whh = layer ? Whh1 : Whh0;
        {
            const float4* w4 = (const float4*)(Whh + (size_t)r * HG);
#pragma unroll
            for (int i = 0; i < 64; ++i) {
                float4 v = w4[i];
                wreg[2 * i]     = (u32)f2h(v.x) | ((u32)f2h(v.y) << 16);
                wreg[2 * i + 1] = (u32)f2h(v.z) | ((u32)f2h(v.w) << 16);
            }
        }
        float c = 0.f;
        hl[tid] = 0.f;
        __syncthreads();
        for (int t = 0; t < T_STEPS; ++t) {
            int s = layer * T_STEPS + t + 1;
            float acc = 0.f;
#pragma unroll
            for (int k2 = 0; k2 < 128; ++k2) {
                u32 wv = wreg[k2];
                float2 hv = *(const float2*)&hl[k2 * 2];
                acc += h2f((u16)wv) * hv.x + h2f((u16)(wv >> 16)) * hv.y;
            }
            garr[tid] = pre[t] + acc;
            __syncthreads();
            if (tid < 64) {
                float ig = sigm(garr[lu]);
                float fg = sigm(garr[64 + lu]);
                float gg = tanhf(garr[128 + lu]);
                float og = sigm(garr[192 + lu]);
                c = fg * c + ig * gg;
                float hn = og * tanhf(c);
                u32 hb; __builtin_memcpy(&hb, &hn, 4);
                u64 pk = ((u64)(u32)s << 32) | (u64)hb;
                __hip_atomic_store(&hbuf[(s & 1) * 256 + unit], pk,
                                   __ATOMIC_RELAXED, __HIP_MEMORY_SCOPE_AGENT);
            }
            u64 v;
            do {
                v = __hip_atomic_load(&hbuf[(s & 1) * 256 + tid],
                                      __ATOMIC_RELAXED, __HIP_MEMORY_SCOPE_AGENT);
            } while ((u32)(v >> 32) != (u32)s);
            u32 lo = (u32)v;
            float hv; __builtin_memcpy(&hv, &lo, 4);
            __syncthreads();
            hl[tid] = hv;
            if (layer == 0) hseqL[t][tid] = hv;
            __syncthreads();
        }
        if (layer == 0) {
            const float4* w4 = (const float4*)(Wih1 + (size_t)r * HG);
#pragma unroll
            for (int t = 0; t < T_STEPS; ++t) pre[t] = 0.f;
            for (int i = 0; i < 64; ++i) {
                float4 wv = w4[i];
#pragma unroll
                for (int t = 0; t < T_STEPS; ++t) {
                    float4 hv = *(const float4*)&hseqL[t][i * 4];
                    pre[t] += wv.x * hv.x + wv.y * hv.y + wv.z * hv.z + wv.w * hv.w;
                }
            }
            float bb = bih1[r] + bhh1[r];
#pragma unroll
            for (int t = 0; t < T_STEPS; ++t) pre[t] += bb;
            __syncthreads();
        }
    }

    if (b == 0 && tid < 8) {
        float s = blin[tid];
        const float* wl = Wlin + tid * HG;
        for (int k = 0; k < HG; ++k) s += hl[k] * wl[k];
        out[tid] = s;
    }
}

// ---------------- orchestration ----------------

extern "C" void kernel_launch(void* const* d_in, const int* in_sizes, int n_in,
                              void* d_out, int out_size, void* d_ws, size_t ws_size,
                              hipStream_t stream) {
    const float* x    = (const float*)d_in[0];
    const int*   edges= (const int*)d_in[1];
    const float* W1   = (const float*)d_in[3];
    const float* b1   = (const float*)d_in[4];
    const float* W2   = (const float*)d_in[5];
    const float* b2   = (const float*)d_in[6];
    const float* Wih0 = (const float*)d_in[7];
    const float* Whh0 = (const float*)d_in[8];
    const float* bih0 = (const float*)d_in[9];
    const float* bhh0 = (const float*)d_in[10];
    const float* Wih1 = (const float*)d_in[11];
    const float* Whh1 = (const float*)d_in[12];
    const float* bih1 = (const float*)d_in[13];
    const float* bhh1 = (const float*)d_in[14];
    const float* Wlin = (const float*)d_in[15];
    const float* blin = (const float*)d_in[16];
    (void)in_sizes; (void)n_in; (void)out_size;

    char* p = (char*)d_ws;
    auto alloc = [&](size_t bytes) -> char* {
        char* q = p; p += (bytes + 255) & ~(size_t)255; return q;
    };
    int*   hist     = (int*)  alloc(sizeof(int)   * T_STEPS * NNODES);
    int*   rowstart = (int*)  alloc(sizeof(int)   * T_STEPS * RS_STRIDE);
    float* dinv     = (float*)alloc(sizeof(float) * T_STEPS * NNODES);
    int*   col      = (int*)  alloc(sizeof(int)   * T_STEPS * NEDGES);
    float* pooled   = (float*)alloc(sizeof(float) * T_STEPS * HG);
    u16*   W1t      = (u16*)  alloc(sizeof(u16)   * HG * FIN);
    u16*   W2t      = (u16*)  alloc(sizeof(u16)   * HG * HG);
    u64*   hbuf     = (u64*)  alloc(sizeof(u64)   * 2 * 256);
    size_t fixed_used = (size_t)(p - (char*)d_ws);

    // xb fp8 (1B), h1b fp8 (1B), aggu bf16 (2B)
    const size_t xb_bytes  = (size_t)T_STEPS * NNODES * FIN;
    const size_t per_g     = (size_t)MPAD * HG * (1 + 2);
    const size_t slack     = 4096 * 16;
    static const int gopts[6] = {12, 6, 4, 3, 2, 1};
    int G = 1;
    for (int i = 0; i < 6; ++i)
        if (fixed_used + xb_bytes + per_g * gopts[i] + slack <= ws_size) { G = gopts[i]; break; }
    u8*  xb   = (u8*) alloc(xb_bytes);
    u8*  h1b  = (u8*) alloc((size_t)G * MPAD * HG);
    u16* aggu = (u16*)alloc(sizeof(u16) * (size_t)G * MPAD * HG);

    hipMemsetAsync(hist, 0, sizeof(int) * T_STEPS * NNODES, stream);

    int tot = T_STEPS * NEDGES;
    hist_kernel<<<(tot + 255) / 256, 256, 0, stream>>>(edges, hist);
    scan_kernel<<<T_STEPS, 1024, 0, stream>>>(hist, rowstart, dinv);
    fill_kernel<<<(tot + 255) / 256, 256, 0, stream>>>(edges, rowstart, hist, col);
    convall<<<30385, 256, 0, stream>>>(x, dinv, xb, W1, W1t, W2, W2t, pooled, hbuf);

    for (int g = 0; g < T_STEPS / G; ++g) {
        int t0 = g * G;
        const u8*    xbg = xb + (size_t)t0 * NNODES * FIN;
        const int*   rsg = rowstart + (size_t)t0 * RS_STRIDE;
        const int*   clg = col + (size_t)t0 * NEDGES;
        const float* dvg = dinv + (size_t)t0 * NNODES;
        int nagg = G * MPAD / 4;
        agg128<<<nagg, 256, 0, stream>>>(xbg, rsg, clg, dvg, aggu);
        gemm_bf16<FIN, false><<<G * 313, 256, 0, stream>>>(aggu, W1t, b1, dvg,
                h1b, nullptr);
        agg256<<<nagg, 256, 0, stream>>>(h1b, rsg, clg, dvg, aggu);
        gemm_bf16<HG, true><<<G * 313, 256, 0, stream>>>(aggu, W2t, b2, nullptr,
                nullptr, pooled + (size_t)t0 * HG);
    }
    lstm4c<<<25, 256, 0, stream>>>(pooled, Wih0, bih0, bhh0, Whh0, Wih1, Whh1,
                                   bih1, bhh1, Wlin, blin, hbuf, (float*)d_out);
}

// Round 13
// 874.579 us; speedup vs baseline: 1.5061x; 1.1027x over previous
//
#include <hip/hip_runtime.h>
#include <hip/hip_bf16.h>
#include <math.h>

#define T_STEPS 12
#define NNODES  20000
#define NEDGES  320000
#define MPAD    20032
#define FIN     128
#define HG      256
#define RS_STRIDE 20032
#define NSL     8
#define SLN     2500     // nodes per dst-slice (8*2500 = 20000)
#define FCH     5        // edge chunks per (t,slice); 320000/5 = 64000

typedef unsigned short u16;
typedef unsigned int   u32;
typedef unsigned char  u8;
typedef unsigned long long u64;
using bf16x8 = __attribute__((ext_vector_type(8))) short;
using f32x4  = __attribute__((ext_vector_type(4))) float;
typedef float v2f __attribute__((ext_vector_type(2)));

__device__ __forceinline__ float bf2f(u16 u) {
    union { u32 i; float f; } v; v.i = ((u32)u) << 16; return v.f;
}
__device__ __forceinline__ u16 f2bf(float f) {
    union { float f; u32 i; } v; v.f = f;
    u32 r = v.i + 0x7fffu + ((v.i >> 16) & 1u);
    return (u16)(r >> 16);
}
__device__ __forceinline__ u16 f2h(float f) {
    _Float16 h = (_Float16)f; u16 u; __builtin_memcpy(&u, &h, 2); return u;
}
__device__ __forceinline__ float h2f(u16 u) {
    _Float16 h; __builtin_memcpy(&h, &u, 2); return (float)h;
}
__device__ __forceinline__ void gload16(const void* g, void* l) {
    __builtin_amdgcn_global_load_lds(
        (const __attribute__((address_space(1))) u32*)g,
        (__attribute__((address_space(3))) u32*)l, 16, 0, 0);
}
__device__ __forceinline__ float sigm(float x) { return 1.f / (1.f + expf(-x)); }

// ---------------- XCD-sliced CSR build ----------------
// dst space split into 8 slices of 2500; slice = bid&7 -> one XCD per slice
// (round-robin block->XCD, validated R6/R12). hist via 10 KB LDS histogram.

__global__ void __launch_bounds__(1024) hist_slice(const int* __restrict__ edges,
        int* __restrict__ hist) {
    __shared__ int lh[SLN];
    int slice = blockIdx.x & 7;
    int rest = blockIdx.x >> 3;
    int c = rest % FCH, t = rest / FCH;
    for (int i = threadIdx.x; i < SLN; i += 1024) lh[i] = 0;
    __syncthreads();
    int lo = slice * SLN;
    const int* db = edges + (size_t)t * 2 * NEDGES + NEDGES;
    int per = NEDGES / FCH;
    int s = c * per, e = s + per;
    for (int i = s + threadIdx.x; i < e; i += 1024) {
        int d = db[i] - lo;
        if ((unsigned)d < SLN) atomicAdd(&lh[d], 1);
    }
    __syncthreads();
    for (int i = threadIdx.x; i < SLN; i += 1024)
        if (lh[i]) atomicAdd(&hist[t * NNODES + lo + i], lh[i]);
}

__global__ void __launch_bounds__(1024) scan_kernel(int* __restrict__ hist,
        int* __restrict__ rowstart, float* __restrict__ dinv) {
    int t = blockIdx.x;
    int tid = threadIdx.x;
    int wid = tid >> 6, lane = tid & 63;
    __shared__ int wsum[16];
    __shared__ int carry_s;
    if (tid == 0) carry_s = 0;
    __syncthreads();
    for (int base = 0; base < NNODES; base += 1024) {
        int i = base + tid;
        int orig = (i < NNODES) ? hist[t * NNODES + i] : 0;
        int v = orig;
#pragma unroll
        for (int off = 1; off < 64; off <<= 1) {
            int n = __shfl_up(v, off);
            if (lane >= off) v += n;
        }
        if (lane == 63) wsum[wid] = v;
        __syncthreads();
        if (wid == 0 && lane < 16) {
            int s = wsum[lane];
#pragma unroll
            for (int off = 1; off < 16; off <<= 1) {
                int n = __shfl_up(s, off);
                if (lane >= off) s += n;
            }
            wsum[lane] = s;
        }
        __syncthreads();
        int incl = v + (wid > 0 ? wsum[wid - 1] : 0) + carry_s;
        int excl = incl - orig;
        if (i < NNODES) {
            rowstart[t * RS_STRIDE + i] = excl;
            dinv[t * NNODES + i] = rsqrtf((float)(orig + 1));
            hist[t * NNODES + i] = 0;
        }
        __syncthreads();
        if (tid == 0) carry_s += wsum[15];
        __syncthreads();
    }
    if (tid == 0) rowstart[t * RS_STRIDE + NNODES] = carry_s;
}

__global__ void __launch_bounds__(1024) fill_slice(const int* __restrict__ edges,
        const int* __restrict__ rowstart, int* __restrict__ cursor,
        int* __restrict__ col) {
    int slice = blockIdx.x & 7;
    int rest = blockIdx.x >> 3;
    int c = rest % FCH, t = rest / FCH;
    int lo = slice * SLN, hi = lo + SLN;
    const int* sb = edges + (size_t)t * 2 * NEDGES;
    const int* db = sb + NEDGES;
    int per = NEDGES / FCH;
    int s = c * per, e = s + per;
    for (int i = s + (int)threadIdx.x; i < e; i += 1024) {
        int d = db[i];
        if (d >= lo && d < hi) {
            int sn = sb[i];
            int pos = rowstart[t * RS_STRIDE + d] + atomicAdd(&cursor[t * NNODES + d], 1);
            col[(size_t)t * NEDGES + pos] = sn;
        }
    }
}

// ---------------- merged conversions: xb fp8 premult, W1t, W2t, zero pooled+hbuf ----------------

__global__ void __launch_bounds__(256) convall(
        const float* __restrict__ x, const float* __restrict__ dinv, u8* __restrict__ xb,
        const float* __restrict__ W1, u16* __restrict__ W1t,
        const float* __restrict__ W2, u16* __restrict__ W2t,
        float* __restrict__ pooled, u64* __restrict__ hbuf) {
    int bid = blockIdx.x;
    int tid = threadIdx.x;
    if (bid < 30000) {
        int idx = bid * 256 + tid;
        int row = idx >> 5, q = idx & 31;              // 32 quads of 4 elems per row
        float dn = dinv[row];
        float4 v = *(const float4*)&x[(size_t)row * FIN + q * 4];
        int p = __builtin_amdgcn_cvt_pk_fp8_f32(dn * v.x, dn * v.y, 0, false);
        p = __builtin_amdgcn_cvt_pk_fp8_f32(dn * v.z, dn * v.w, p, true);
        ((u32*)xb)[(size_t)row * 32 + q] = (u32)p;
    } else if (bid < 30128) {
        int idx = (bid - 30000) * 256 + tid;      // [256][128]
        int n = idx / FIN, k = idx - n * FIN;
        W1t[idx] = f2bf(W1[k * HG + n]);
    } else if (bid < 30384) {
        int idx = (bid - 30128) * 256 + tid;      // [256][256]
        int n = idx >> 8, k = idx & 255;
        W2t[idx] = f2bf(W2[k * HG + n]);
    } else {
        for (int i = tid; i < T_STEPS * HG; i += 256) pooled[i] = 0.f;
        for (int i = tid; i < 512; i += 256) hbuf[i] = 0ull;   // tags=0 < first step 1
    }
}

// ---------------- pull aggregation, fp8 payload (R5 structure: 1 node/wave, 16-deep) ----------------
// payload rows PRE-SCALED by dinv and stored fp8 e4m3; accumulate f32; output bf16.
// out[d] = dinv[d]*(row[d] + sum_{s->d} row[s]).

__global__ void __launch_bounds__(256) agg128(const u8* __restrict__ xb,
        const int* __restrict__ rowstart, const int* __restrict__ col,
        const float* __restrict__ dinv, u16* __restrict__ out) {
    int glob = (blockIdx.x << 2) + (threadIdx.x >> 6);
    int lane = threadIdx.x & 63;
    int t = glob / MPAD, node = glob - t * MPAD;
    u16* orow = out + ((size_t)glob) * FIN;
    if (node >= NNODES) { *(u32*)&orow[lane << 1] = 0; return; }
    const u8* xt = xb + (size_t)t * NNODES * FIN;    // fp8 rows, 128 B each
    const int* cb = col + (size_t)t * NEDGES;
    int o2 = lane << 1;
    u32 pv = *(const u16*)&xt[(size_t)node * FIN + o2];
    v2f f = __builtin_amdgcn_cvt_pk_f32_fp8((int)pv, false);
    float ax = f[0], ay = f[1];
    int s0 = rowstart[t * RS_STRIDE + node], s1 = rowstart[t * RS_STRIDE + node + 1];
    int e = s0;
    for (; e + 16 <= s1; e += 16) {
        int ix[16]; u32 rv[16];
#pragma unroll
        for (int j = 0; j < 16; ++j) ix[j] = cb[e + j];
#pragma unroll
        for (int j = 0; j < 16; ++j) rv[j] = *(const u16*)&xt[(size_t)ix[j] * FIN + o2];
#pragma unroll
        for (int j = 0; j < 16; ++j) {
            v2f g = __builtin_amdgcn_cvt_pk_f32_fp8((int)rv[j], false);
            ax += g[0]; ay += g[1];
        }
    }
    for (; e + 4 <= s1; e += 4) {
        int ix[4]; u32 rv[4];
#pragma unroll
        for (int j = 0; j < 4; ++j) ix[j] = cb[e + j];
#pragma unroll
        for (int j = 0; j < 4; ++j) rv[j] = *(const u16*)&xt[(size_t)ix[j] * FIN + o2];
#pragma unroll
        for (int j = 0; j < 4; ++j) {
            v2f g = __builtin_amdgcn_cvt_pk_f32_fp8((int)rv[j], false);
            ax += g[0]; ay += g[1];
        }
    }
    for (; e < s1; ++e) {
        u32 rv = *(const u16*)&xt[(size_t)cb[e] * FIN + o2];
        v2f g = __builtin_amdgcn_cvt_pk_f32_fp8((int)rv, false);
        ax += g[0]; ay += g[1];
    }
    float dn = dinv[t * NNODES + node];
    u32 packed = (u32)f2bf(dn * ax) | ((u32)f2bf(dn * ay) << 16);
    *(u32*)&orow[o2] = packed;
}

__global__ void __launch_bounds__(256) agg256(const u8* __restrict__ xin,
        const int* __restrict__ rowstart, const int* __restrict__ col,
        const float* __restrict__ dinv, u16* __restrict__ out) {
    int glob = (blockIdx.x << 2) + (threadIdx.x >> 6);
    int lane = threadIdx.x & 63;
    int t = glob / MPAD, node = glob - t * MPAD;
    u16* orow = out + ((size_t)glob) * HG;
    if (node >= NNODES) { *(ushort4*)&orow[lane << 2] = make_ushort4(0, 0, 0, 0); return; }
    const u8* xt = xin + (size_t)t * MPAD * HG;      // fp8 rows, 256 B each
    const int* cb = col + (size_t)t * NEDGES;
    int o4 = lane << 2;
    u32 pv = *(const u32*)&xt[(size_t)node * HG + o4];
    v2f f01 = __builtin_amdgcn_cvt_pk_f32_fp8((int)pv, false);
    v2f f23 = __builtin_amdgcn_cvt_pk_f32_fp8((int)pv, true);
    float a0 = f01[0], a1 = f01[1], a2 = f23[0], a3 = f23[1];
    int s0 = rowstart[t * RS_STRIDE + node], s1 = rowstart[t * RS_STRIDE + node + 1];
    int e = s0;
    for (; e + 16 <= s1; e += 16) {
        int ix[16]; u32 rv[16];
#pragma unroll
        for (int j = 0; j < 16; ++j) ix[j] = cb[e + j];
#pragma unroll
        for (int j = 0; j < 16; ++j) rv[j] = *(const u32*)&xt[(size_t)ix[j] * HG + o4];
#pragma unroll
        for (int j = 0; j < 16; ++j) {
            v2f g01 = __builtin_amdgcn_cvt_pk_f32_fp8((int)rv[j], false);
            v2f g23 = __builtin_amdgcn_cvt_pk_f32_fp8((int)rv[j], true);
            a0 += g01[0]; a1 += g01[1]; a2 += g23[0]; a3 += g23[1];
        }
    }
    for (; e + 4 <= s1; e += 4) {
        int ix[4]; u32 rv[4];
#pragma unroll
        for (int j = 0; j < 4; ++j) ix[j] = cb[e + j];
#pragma unroll
        for (int j = 0; j < 4; ++j) rv[j] = *(const u32*)&xt[(size_t)ix[j] * HG + o4];
#pragma unroll
        for (int j = 0; j < 4; ++j) {
            v2f g01 = __builtin_amdgcn_cvt_pk_f32_fp8((int)rv[j], false);
            v2f g23 = __builtin_amdgcn_cvt_pk_f32_fp8((int)rv[j], true);
            a0 += g01[0]; a1 += g01[1]; a2 += g23[0]; a3 += g23[1];
        }
    }
    for (; e < s1; ++e) {
        u32 rv = *(const u32*)&xt[(size_t)cb[e] * HG + o4];
        v2f g01 = __builtin_amdgcn_cvt_pk_f32_fp8((int)rv, false);
        v2f g23 = __builtin_amdgcn_cvt_pk_f32_fp8((int)rv, true);
        a0 += g01[0]; a1 += g01[1]; a2 += g23[0]; a3 += g23[1];
    }
    float dn = dinv[t * NNODES + node];
    ushort4 o;
    o.x = f2bf(dn * a0); o.y = f2bf(dn * a1); o.z = f2bf(dn * a2); o.w = f2bf(dn * a3);
    *(ushort4*)&orow[o4] = o;
}

// ---------------- bf16 MFMA GEMM, 64M x 256N tile (verified R7-R12) ----------------
// !POOL: C[row] = fp8( dscale[row]*relu(acc+bias) ); POOL: per-t column sums.

template <int K, bool POOL>
__global__ __launch_bounds__(256) void gemm_bf16(
        const u16* __restrict__ A, const u16* __restrict__ Bt,
        const float* __restrict__ bias, const float* __restrict__ dscale,
        u8* __restrict__ C, float* __restrict__ pool) {
    __shared__ u16 As[64 * 64];      // 8 KB
    __shared__ u16 Bs[256 * 64];     // 32 KB
    __shared__ float csum[HG];
    int tid = threadIdx.x;
    int bm = blockIdx.x * 64;
    int t8 = tid >> 3, sl = tid & 7;
    int lane = tid & 63, w = tid >> 6;
    int r0 = lane & 15, gq = lane >> 4;
    int tblk = blockIdx.x / 313;

    f32x4 acc[4][4] = {};

    for (int k0 = 0; k0 < K; k0 += 64) {
#pragma unroll
        for (int i = 0; i < 2; ++i) {
            int r = i * 32 + t8;
            int ch = sl ^ (r & 7);
            gload16(A + (size_t)(bm + r) * K + k0 + ch * 8, &As[i * 2048 + tid * 8]);
        }
#pragma unroll
        for (int i = 0; i < 8; ++i) {
            int r = i * 32 + t8;
            int ch = sl ^ (r & 7);
            gload16(Bt + (size_t)r * K + k0 + ch * 8, &Bs[i * 2048 + tid * 8]);
        }
        __syncthreads();
#pragma unroll
        for (int kk = 0; kk < 2; ++kk) {
            bf16x8 a[4], b[4];
#pragma unroll
            for (int mi = 0; mi < 4; ++mi) {
                int R = mi * 16 + r0;
                int s = (kk * 4 + gq) ^ (R & 7);
                a[mi] = *(const bf16x8*)&As[R * 64 + s * 8];
            }
#pragma unroll
            for (int ni = 0; ni < 4; ++ni) {
                int R = w * 64 + ni * 16 + r0;
                int s = (kk * 4 + gq) ^ (R & 7);
                b[ni] = *(const bf16x8*)&Bs[R * 64 + s * 8];
            }
#pragma unroll
            for (int mi = 0; mi < 4; ++mi)
#pragma unroll
                for (int ni = 0; ni < 4; ++ni)
                    acc[mi][ni] = __builtin_amdgcn_mfma_f32_16x16x32_bf16(
                        a[mi], b[ni], acc[mi][ni], 0, 0, 0);
        }
        __syncthreads();
    }

    if (!POOL) {
#pragma unroll
        for (int ni = 0; ni < 4; ++ni) {
            int colg = w * 64 + ni * 16 + r0;
            float b = bias[colg];
#pragma unroll
            for (int mi = 0; mi < 4; ++mi) {
                int rbase = bm + mi * 16 + gq * 4;
#pragma unroll
                for (int q = 0; q < 4; ++q) {
                    int row = rbase + q;
                    int rloc = row - tblk * MPAD;
                    float sc = (rloc < NNODES) ? dscale[tblk * NNODES + rloc] : 0.f;
                    float val = sc * fmaxf(acc[mi][ni][q] + b, 0.f);
                    int p = __builtin_amdgcn_cvt_pk_fp8_f32(val, val, 0, false);
                    C[(size_t)row * HG + colg] = (u8)(p & 0xff);
                }
            }
        }
    } else {
        csum[tid] = 0.f;
        __syncthreads();
#pragma unroll
        for (int ni = 0; ni < 4; ++ni) {
            int colg = w * 64 + ni * 16 + r0;
            float b = bias[colg];
            float s = 0.f;
#pragma unroll
            for (int mi = 0; mi < 4; ++mi) {
                int rbase = bm + mi * 16 + gq * 4;
#pragma unroll
                for (int q = 0; q < 4; ++q) {
                    int row = rbase + q;
                    int rloc = row - tblk * MPAD;
                    if (rloc < NNODES) s += fmaxf(acc[mi][ni][q] + b, 0.f);
                }
            }
            atomicAdd(&csum[colg], s);
        }
        __syncthreads();
        atomicAdd(&pool[tblk * HG + tid], csum[tid]);
    }
}

// ---------------- 4-block cooperative LSTM, tagged-payload sync, SAME-XCD placement ----------------
// (verified R12)

__global__ void __launch_bounds__(256, 1) lstm4c(
        const float* __restrict__ pooled,
        const float* __restrict__ Wih0, const float* __restrict__ bih0,
        const float* __restrict__ bhh0,
        const float* __restrict__ Whh0, const float* __restrict__ Wih1,
        const float* __restrict__ Whh1,
        const float* __restrict__ bih1, const float* __restrict__ bhh1,
        const float* __restrict__ Wlin, const float* __restrict__ blin,
        u64* hbuf, float* __restrict__ out) {
    if (blockIdx.x & 7) return;                    // workers: 0,8,16,24 -> same XCD
    __shared__ float xs[T_STEPS][HG];
    __shared__ float hseqL[T_STEPS][HG];
    __shared__ float hl[HG];
    __shared__ float garr[256];
    int tid = threadIdx.x;
    int b = blockIdx.x >> 3;
    int lu = tid & 63;
    int unit = b * 64 + lu;
    int r = (tid >> 6) * 256 + unit;

    for (int i = tid; i < T_STEPS * HG; i += 256)
        ((float*)xs)[i] = pooled[i] * (1.f / (float)NNODES);
    __syncthreads();

    float pre[T_STEPS];
    {
        const float4* w4 = (const float4*)(Wih0 + (size_t)r * HG);
#pragma unroll
        for (int t = 0; t < T_STEPS; ++t) pre[t] = 0.f;
        for (int i = 0; i < 64; ++i) {
            float4 wv = w4[i];
#pragma unroll
            for (int t = 0; t < T_STEPS; ++t) {
                float4 xv = *(const float4*)&xs[t][i * 4];
                pre[t] += wv.x * xv.x + wv.y * xv.y + wv.z * xv.z + wv.w * xv.w;
            }
        }
        float bb = bih0[r] + bhh0[r];
#pragma unroll
        for (int t = 0; t < T_STEPS; ++t) pre[t] += bb;
    }

    u32 wreg[128];
    for (int layer = 0; layer < 2; ++layer) {
        const float* Whh = layer ? Whh1 : Whh0;
        {
            const float4* w4 = (const float4*)(Whh + (size_t)r * HG);
#pragma unroll
            for (int i = 0; i < 64; ++i) {
                float4 v = w4[i];
                wreg[2 * i]     = (u32)f2h(v.x) | ((u32)f2h(v.y) << 16);
                wreg[2 * i + 1] = (u32)f2h(v.z) | ((u32)f2h(v.w) << 16);
            }
        }
        float c = 0.f;
        hl[tid] = 0.f;
        __syncthreads();
        for (int t = 0; t < T_STEPS; ++t) {
            int s = layer * T_STEPS + t + 1;
            float acc = 0.f;
#pragma unroll
            for (int k2 = 0; k2 < 128; ++k2) {
                u32 wv = wreg[k2];
                float2 hv = *(const float2*)&hl[k2 * 2];
                acc += h2f((u16)wv) * hv.x + h2f((u16)(wv >> 16)) * hv.y;
            }
            garr[tid] = pre[t] + acc;
            __syncthreads();
            if (tid < 64) {
                float ig = sigm(garr[lu]);
                float fg = sigm(garr[64 + lu]);
                float gg = tanhf(garr[128 + lu]);
                float og = sigm(garr[192 + lu]);
                c = fg * c + ig * gg;
                float hn = og * tanhf(c);
                u32 hb; __builtin_memcpy(&hb, &hn, 4);
                u64 pk = ((u64)(u32)s << 32) | (u64)hb;
                __hip_atomic_store(&hbuf[(s & 1) * 256 + unit], pk,
                                   __ATOMIC_RELAXED, __HIP_MEMORY_SCOPE_AGENT);
            }
            u64 v;
            do {
                v = __hip_atomic_load(&hbuf[(s & 1) * 256 + tid],
                                      __ATOMIC_RELAXED, __HIP_MEMORY_SCOPE_AGENT);
            } while ((u32)(v >> 32) != (u32)s);
            u32 lo = (u32)v;
            float hv; __builtin_memcpy(&hv, &lo, 4);
            __syncthreads();
            hl[tid] = hv;
            if (layer == 0) hseqL[t][tid] = hv;
            __syncthreads();
        }
        if (layer == 0) {
            const float4* w4 = (const float4*)(Wih1 + (size_t)r * HG);
#pragma unroll
            for (int t = 0; t < T_STEPS; ++t) pre[t] = 0.f;
            for (int i = 0; i < 64; ++i) {
                float4 wv = w4[i];
#pragma unroll
                for (int t = 0; t < T_STEPS; ++t) {
                    float4 hv = *(const float4*)&hseqL[t][i * 4];
                    pre[t] += wv.x * hv.x + wv.y * hv.y + wv.z * hv.z + wv.w * hv.w;
                }
            }
            float bb = bih1[r] + bhh1[r];
#pragma unroll
            for (int t = 0; t < T_STEPS; ++t) pre[t] += bb;
            __syncthreads();
        }
    }

    if (b == 0 && tid < 8) {
        float s = blin[tid];
        const float* wl = Wlin + tid * HG;
        for (int k = 0; k < HG; ++k) s += hl[k] * wl[k];
        out[tid] = s;
    }
}

// ---------------- orchestration ----------------

extern "C" void kernel_launch(void* const* d_in, const int* in_sizes, int n_in,
                              void* d_out, int out_size, void* d_ws, size_t ws_size,
                              hipStream_t stream) {
    const float* x    = (const float*)d_in[0];
    const int*   edges= (const int*)d_in[1];
    const float* W1   = (const float*)d_in[3];
    const float* b1   = (const float*)d_in[4];
    const float* W2   = (const float*)d_in[5];
    const float* b2   = (const float*)d_in[6];
    const float* Wih0 = (const float*)d_in[7];
    const float* Whh0 = (const float*)d_in[8];
    const float* bih0 = (const float*)d_in[9];
    const float* bhh0 = (const float*)d_in[10];
    const float* Wih1 = (const float*)d_in[11];
    const float* Whh1 = (const float*)d_in[12];
    const float* bih1 = (const float*)d_in[13];
    const float* bhh1 = (const float*)d_in[14];
    const float* Wlin = (const float*)d_in[15];
    const float* blin = (const float*)d_in[16];
    (void)in_sizes; (void)n_in; (void)out_size;

    char* p = (char*)d_ws;
    auto alloc = [&](size_t bytes) -> char* {
        char* q = p; p += (bytes + 255) & ~(size_t)255; return q;
    };
    int*   hist     = (int*)  alloc(sizeof(int)   * T_STEPS * NNODES);
    int*   rowstart = (int*)  alloc(sizeof(int)   * T_STEPS * RS_STRIDE);
    float* dinv     = (float*)alloc(sizeof(float) * T_STEPS * NNODES);
    int*   col      = (int*)  alloc(sizeof(int)   * T_STEPS * NEDGES);
    float* pooled   = (float*)alloc(sizeof(float) * T_STEPS * HG);
    u16*   W1t      = (u16*)  alloc(sizeof(u16)   * HG * FIN);
    u16*   W2t      = (u16*)  alloc(sizeof(u16)   * HG * HG);
    u64*   hbuf     = (u64*)  alloc(sizeof(u64)   * 2 * 256);
    size_t fixed_used = (size_t)(p - (char*)d_ws);

    // xb fp8 (1B), h1b fp8 (1B), aggu bf16 (2B)
    const size_t xb_bytes  = (size_t)T_STEPS * NNODES * FIN;
    const size_t per_g     = (size_t)MPAD * HG * (1 + 2);
    const size_t slack     = 4096 * 16;
    static const int gopts[6] = {12, 6, 4, 3, 2, 1};
    int G = 1;
    for (int i = 0; i < 6; ++i)
        if (fixed_used + xb_bytes + per_g * gopts[i] + slack <= ws_size) { G = gopts[i]; break; }
    u8*  xb   = (u8*) alloc(xb_bytes);
    u8*  h1b  = (u8*) alloc((size_t)G * MPAD * HG);
    u16* aggu = (u16*)alloc(sizeof(u16) * (size_t)G * MPAD * HG);

    hipMemsetAsync(hist, 0, sizeof(int) * T_STEPS * NNODES, stream);

    hist_slice<<<T_STEPS * FCH * NSL, 1024, 0, stream>>>(edges, hist);
    scan_kernel<<<T_STEPS, 1024, 0, stream>>>(hist, rowstart, dinv);
    fill_slice<<<T_STEPS * FCH * NSL, 1024, 0, stream>>>(edges, rowstart, hist, col);
    convall<<<30385, 256, 0, stream>>>(x, dinv, xb, W1, W1t, W2, W2t, pooled, hbuf);

    for (int g = 0; g < T_STEPS / G; ++g) {
        int t0 = g * G;
        const u8*    xbg = xb + (size_t)t0 * NNODES * FIN;
        const int*   rsg = rowstart + (size_t)t0 * RS_STRIDE;
        const int*   clg = col + (size_t)t0 * NEDGES;
        const float* dvg = dinv + (size_t)t0 * NNODES;
        int nagg = G * MPAD / 4;
        agg128<<<nagg, 256, 0, stream>>>(xbg, rsg, clg, dvg, aggu);
        gemm_bf16<FIN, false><<<G * 313, 256, 0, stream>>>(aggu, W1t, b1, dvg,
                h1b, nullptr);
        agg256<<<nagg, 256, 0, stream>>>(h1b, rsg, clg, dvg, aggu);
        gemm_bf16<HG, true><<<G * 313, 256, 0, stream>>>(aggu, W2t, b2, nullptr,
                nullptr, pooled + (size_t)t0 * HG);
    }
    lstm4c<<<25, 256, 0, stream>>>(pooled, Wih0, bih0, bhh0, Whh0, Wih1, Whh1,
                                   bih1, bhh1, Wlin, blin, hbuf, (float*)d_out);
}